// Round 3
// baseline (2355.717 us; speedup 1.0000x reference)
//
#include <hip/hip_runtime.h>
#include <math.h>

typedef __bf16 bf16;
typedef __bf16 bf16x8 __attribute__((ext_vector_type(8)));
typedef float f32x4 __attribute__((ext_vector_type(4)));

#define N_NODES 10000
#define N_EDGES 80000
#define N_GRAPHS 64

__device__ inline unsigned f2ord(float f){
  unsigned u = __float_as_uint(f);
  return (u & 0x80000000u) ? ~u : (u | 0x80000000u);
}
__device__ inline float ord2f(unsigned u){
  return (u & 0x80000000u) ? __uint_as_float(u & 0x7fffffffu) : __uint_as_float(~u);
}

__global__ __launch_bounds__(256) void zero_u32(unsigned* __restrict__ p, int n){
  int i = blockIdx.x*256 + threadIdx.x;
  if (i < n) p[i] = 0u;
}

// ---- dtype detection: bf16 vs fp32 stored in the float-tensor buffers ----
// Interpret raw as bf16; exponent >= 0xC0 (|v| >= 2^65) cannot occur for
// N(0,1)-scale bf16 data but occurs in ~25% of fp32 low-half words.
__global__ __launch_bounds__(256) void detect_f32_k(const unsigned short* __restrict__ raw, int n,
                                                    int* __restrict__ flagF){
  int i = blockIdx.x*256 + threadIdx.x;
  if (i < n){
    unsigned e = (raw[i] >> 7) & 0xFFu;
    if (e >= 0xC0u) atomicOr(flagF, 1);
  }
}

// normalize any float tensor to bf16
__global__ __launch_bounds__(256) void to_bf16_k(const void* __restrict__ raw, bf16* __restrict__ out,
                                                 int n, const int* __restrict__ flagF){
  int i = blockIdx.x*256 + threadIdx.x;
  if (i >= n) return;
  if (*flagF) out[i] = (bf16)((const float*)raw)[i];
  else        out[i] = ((const bf16*)raw)[i];
}

// edge_index may arrive as int32 or int64; detect on-device (int64 -> odd int32 words all 0)
__global__ __launch_bounds__(256) void detect_i64(const int* __restrict__ raw, int* __restrict__ flag){
  int i = blockIdx.x*256 + threadIdx.x;
  if (i < 4000 && raw[2*i+1] != 0) atomicOr(flag, 1);   // flag!=0 => int32
}

__global__ __launch_bounds__(256) void conv_idx(const int* __restrict__ ei_raw,
                                                const int* __restrict__ b_raw,
                                                const int* __restrict__ flag,
                                                int* __restrict__ src, int* __restrict__ dst,
                                                int* __restrict__ bat){
  int i = blockIdx.x*256 + threadIdx.x;
  bool i32 = (*flag != 0);
  if (i < N_EDGES){
    int s = i32 ? ei_raw[i]   : ei_raw[2*i];
    int d = i32 ? ei_raw[N_EDGES + i] : ei_raw[2*(N_EDGES + i)];
    src[i] = min(max(s, 0), N_NODES-1);
    dst[i] = min(max(d, 0), N_NODES-1);
  }
  if (i < N_NODES){
    int b = i32 ? b_raw[i] : b_raw[2*i];
    bat[i] = min(max(b, 0), N_GRAPHS-1);
  }
}

// ---------------- CSR build ----------------
__global__ __launch_bounds__(256) void count_deg(const int* __restrict__ dst, int* __restrict__ cnt){
  int e = blockIdx.x*256 + threadIdx.x;
  if (e < N_EDGES) atomicAdd(&cnt[dst[e]], 1);
}

__global__ __launch_bounds__(1024) void scan_deg(const int* __restrict__ cnt,
                                                 int* __restrict__ row_ptr,
                                                 int* __restrict__ fill, int N){
  __shared__ int sdata[1024];
  __shared__ int soff;
  int tid = threadIdx.x;
  if (tid == 0){ soff = 0; row_ptr[0] = 0; }
  __syncthreads();
  for (int base = 0; base < N; base += 1024){
    int i = base + tid;
    int v = (i < N) ? cnt[i] : 0;
    sdata[tid] = v;
    __syncthreads();
    for (int d = 1; d < 1024; d <<= 1){
      int t = (tid >= d) ? sdata[tid - d] : 0;
      __syncthreads();
      sdata[tid] += t;
      __syncthreads();
    }
    int incl  = sdata[tid] + soff;
    int total = sdata[1023];
    if (i < N){ row_ptr[i+1] = incl; fill[i] = incl - v; }
    __syncthreads();
    if (tid == 0) soff += total;
    __syncthreads();
  }
}

__global__ __launch_bounds__(256) void fill_csr(const int* __restrict__ dst,
                                                int* __restrict__ fill, int* __restrict__ eids){
  int e = blockIdx.x*256 + threadIdx.x;
  if (e < N_EDGES){
    int p = atomicAdd(&fill[dst[e]], 1);
    eids[p] = e;
  }
}

// ---------------- weight transpose  [K][N] -> [N][K] ----------------
__global__ __launch_bounds__(256) void transpose_bf16(const bf16* __restrict__ in, bf16* __restrict__ out,
                                                      int K, int N){
  __shared__ bf16 t[32][33];
  int bx = blockIdx.x;            // N/32
  int by = blockIdx.y;            // K/32
  int x = threadIdx.x & 31, y = threadIdx.x >> 5;
  #pragma unroll
  for (int i = 0; i < 4; ++i){
    int r = by*32 + y + i*8;
    t[y + i*8][x] = in[(size_t)r*N + bx*32 + x];
  }
  __syncthreads();
  #pragma unroll
  for (int i = 0; i < 4; ++i){
    int r = bx*32 + y + i*8;
    out[(size_t)r*K + by*32 + x] = t[x][y + i*8];
  }
}

// ---------------- GEMM: C[M][N] = A[M][K] @ B(given as Bt[N][K]) + bias ----------------
__global__ __launch_bounds__(256)
void gemm_bias(const bf16* __restrict__ A, const bf16* __restrict__ Bt,
               const bf16* __restrict__ bias, bf16* __restrict__ Cout,
               int M, int N, int K)
{
  __shared__ bf16 As[128][72];
  __shared__ bf16 Bs[128][72];
  const int tid = threadIdx.x;
  const int lane = tid & 63;
  const int wave = tid >> 6;
  const int m0 = blockIdx.y * 128, n0 = blockIdx.x * 128;
  const int wm = (wave >> 1) * 64, wn = (wave & 1) * 64;
  const int l15 = lane & 15, l4 = lane >> 4;

  f32x4 acc[4][4] = {};

  for (int k0 = 0; k0 < K; k0 += 64){
    #pragma unroll
    for (int it = 0; it < 4; ++it){
      int v = tid + it*256;
      int row = v >> 3, colv = v & 7;
      bf16x8 av;
      #pragma unroll
      for (int j = 0; j < 8; ++j) av[j] = (bf16)0.0f;
      int grow = m0 + row;
      if (grow < M) av = *(const bf16x8*)(A + (size_t)grow*K + k0 + colv*8);
      *(bf16x8*)&As[row][colv*8] = av;
    }
    #pragma unroll
    for (int it = 0; it < 4; ++it){
      int v = tid + it*256;
      int row = v >> 3, colv = v & 7;
      bf16x8 bv = *(const bf16x8*)(Bt + (size_t)(n0 + row)*K + k0 + colv*8);
      *(bf16x8*)&Bs[row][colv*8] = bv;
    }
    __syncthreads();
    #pragma unroll
    for (int kt = 0; kt < 2; ++kt){
      bf16x8 af[4], bfr[4];
      #pragma unroll
      for (int mt = 0; mt < 4; ++mt) af[mt]  = *(const bf16x8*)&As[wm + mt*16 + l15][kt*32 + l4*8];
      #pragma unroll
      for (int nt = 0; nt < 4; ++nt) bfr[nt] = *(const bf16x8*)&Bs[wn + nt*16 + l15][kt*32 + l4*8];
      #pragma unroll
      for (int mt = 0; mt < 4; ++mt)
        #pragma unroll
        for (int nt = 0; nt < 4; ++nt)
          acc[mt][nt] = __builtin_amdgcn_mfma_f32_16x16x32_bf16(af[mt], bfr[nt], acc[mt][nt], 0, 0, 0);
    }
    __syncthreads();
  }

  #pragma unroll
  for (int nt = 0; nt < 4; ++nt){
    int col = n0 + wn + nt*16 + l15;
    float bv = (float)bias[col];
    #pragma unroll
    for (int mt = 0; mt < 4; ++mt){
      int rbase = m0 + wm + mt*16 + l4*4;
      #pragma unroll
      for (int r = 0; r < 4; ++r){
        int row = rbase + r;
        if (row < M) Cout[(size_t)row*N + col] = (bf16)(acc[mt][nt][r] + bv);
      }
    }
  }
}

// ---------------- edge scores for G heads ----------------
__global__ __launch_bounds__(256) void edge_scores(const bf16* __restrict__ Q, const bf16* __restrict__ K,
                                                   const int* __restrict__ src, const int* __restrict__ dst,
                                                   float* __restrict__ scores, int G, int C, float scale){
  int e = blockIdx.x*4 + (threadIdx.x >> 6);
  if (e >= N_EDGES) return;
  int lane = threadIdx.x & 63;
  const bf16* qrow = Q + (size_t)dst[e]*((size_t)G*C);
  const bf16* krow = K + (size_t)src[e]*((size_t)G*C);
  int epl = C >> 6;
  for (int h = 0; h < G; ++h){
    float s = 0.f;
    const bf16* q = qrow + h*C;
    const bf16* k = krow + h*C;
    for (int j = 0; j < epl; ++j){
      int idx = j*64 + lane;
      s += (float)q[idx] * (float)k[idx];
    }
    #pragma unroll
    for (int o = 32; o; o >>= 1) s += __shfl_xor(s, o, 64);
    if (lane == 0) scores[(size_t)e*G + h] = s * scale;
  }
}

// ---------------- per-node softmax + weighted aggregate into f32 accumulator ----------------
__global__ __launch_bounds__(64) void aggregate_acc(const float* __restrict__ scores, const bf16* __restrict__ V,
                                                    const int* __restrict__ row_ptr, const int* __restrict__ eids,
                                                    const int* __restrict__ src, float* __restrict__ accb,
                                                    int G, int C){
  int n = blockIdx.x;
  int lane = threadIdx.x;
  int beg = row_ptr[n], deg = row_ptr[n+1] - beg;
  if (deg == 0) return;
  int epl = C >> 6;

  for (int h = 0; h < G; ++h){
    float m = -3.4e38f;
    for (int i = lane; i < deg; i += 64)
      m = fmaxf(m, scores[(size_t)eids[beg+i]*G + h]);
    #pragma unroll
    for (int o = 32; o; o >>= 1) m = fmaxf(m, __shfl_xor(m, o, 64));
    float ssum = 0.f;
    for (int i = lane; i < deg; i += 64)
      ssum += __expf(scores[(size_t)eids[beg+i]*G + h] - m);
    #pragma unroll
    for (int o = 32; o; o >>= 1) ssum += __shfl_xor(ssum, o, 64);
    float inv = 1.f/(ssum + 1e-16f);
    float acc[8];
    #pragma unroll
    for (int j = 0; j < 8; ++j) acc[j] = 0.f;
    for (int i = 0; i < deg; ++i){
      int e = eids[beg+i];
      float w = __expf(scores[(size_t)e*G + h] - m) * inv;
      const bf16* vr = V + (size_t)src[e]*((size_t)G*C) + h*C;
      for (int j = 0; j < epl; ++j) acc[j] += w * (float)vr[j*64 + lane];
    }
    for (int j = 0; j < epl; ++j)
      accb[(size_t)n*C + j*64 + lane] += acc[j];
  }
}

// ---------------- finalize: h = elu(acc/8 + skip) ----------------
__global__ __launch_bounds__(256) void finalize_layer(const float* __restrict__ accb, const bf16* __restrict__ skip,
                                                      bf16* __restrict__ hout, int total){
  int i = blockIdx.x*256 + threadIdx.x;
  if (i < total){
    float v = accb[i]*0.125f + (float)skip[i];
    v = (v > 0.f) ? v : (__expf(v) - 1.f);
    hout[i] = (bf16)v;
  }
}

// ---------------- pooling ----------------
__global__ __launch_bounds__(256) void gate_compute(const bf16* __restrict__ h, const bf16* __restrict__ wg,
                                                    const bf16* __restrict__ bg, float* __restrict__ gate){
  int n = blockIdx.x*4 + (threadIdx.x >> 6);
  if (n >= N_NODES) return;
  int lane = threadIdx.x & 63;
  const bf16* hr = h + (size_t)n*128;
  float s = (float)hr[lane]*(float)wg[lane] + (float)hr[64+lane]*(float)wg[64+lane];
  #pragma unroll
  for (int o = 32; o; o >>= 1) s += __shfl_xor(s, o, 64);
  if (lane == 0) gate[n] = s + (float)bg[0];
}

__global__ __launch_bounds__(256) void gate_max(const float* __restrict__ gate, const int* __restrict__ bat,
                                                unsigned* __restrict__ gmax){
  int n = blockIdx.x*256 + threadIdx.x;
  if (n < N_NODES) atomicMax(&gmax[bat[n]], f2ord(gate[n]));
}

__global__ __launch_bounds__(256) void gate_expsum(float* __restrict__ gate, const int* __restrict__ bat,
                                                   const unsigned* __restrict__ gmax, float* __restrict__ gsum){
  int n = blockIdx.x*256 + threadIdx.x;
  if (n < N_NODES){
    float e = __expf(gate[n] - ord2f(gmax[bat[n]]));
    gate[n] = e;
    atomicAdd(&gsum[bat[n]], e);
  }
}

__global__ __launch_bounds__(256) void pool_weighted(const float* __restrict__ gate, const float* __restrict__ gsum,
                                                     const int* __restrict__ bat, const bf16* __restrict__ h,
                                                     float* __restrict__ gacc){
  int n = blockIdx.x*4 + (threadIdx.x >> 6);
  if (n >= N_NODES) return;
  int lane = threadIdx.x & 63;
  int b = bat[n];
  float w = gate[n]/(gsum[b] + 1e-16f);
  atomicAdd(&gacc[b*128 + lane],      w*(float)h[(size_t)n*128 + lane]);
  atomicAdd(&gacc[b*128 + 64 + lane], w*(float)h[(size_t)n*128 + 64 + lane]);
}

// output dtype matches detected input dtype (fp32 if flagF else bf16)
__global__ __launch_bounds__(64) void final_fc(const float* __restrict__ gacc, const bf16* __restrict__ wfc,
                                               const bf16* __restrict__ bfc, void* __restrict__ out,
                                               const int* __restrict__ flagF){
  int g = blockIdx.x;
  int o = threadIdx.x;
  if (o < 10){
    float s = (float)bfc[o];
    for (int c = 0; c < 128; ++c) s += gacc[g*128 + c]*(float)wfc[c*10 + o];
    if (*flagF) ((float*)out)[(size_t)g*10 + o] = s;
    else        ((bf16*)out)[(size_t)g*10 + o]  = (bf16)s;
  }
}

extern "C" void kernel_launch(void* const* d_in, const int* in_sizes, int n_in,
                              void* d_out, int out_size, void* d_ws, size_t ws_size,
                              hipStream_t stream)
{
  const int*  ei    = (const int*)d_in[1];
  const int*  braw  = (const int*)d_in[2];

  // indices of float tensors in d_in (x, 12 weights, 12 biases, w_g, b_g, w_fc, b_fc)
  static const int FIDX[29] = {0,3,4,5,6,7,8,9,10,11,12,13,14,15,16,17,18,
                               19,20,21,22,23,24,25,26,27,28,29,30};

  // ---- workspace plan (adaptive head-group size G) ----
  bf16 *Qg=0, *Kg=0, *Vg=0, *skipb=0, *h1=0, *h2=0, *h3=0;
  bf16 *wt[12];
  bf16 *cv[31];
  float *accb=0, *scores=0, *gate=0;
  int *src=0,*dst=0,*bat=0,*cnt=0,*row_ptr=0,*fillp=0,*eids=0,*flag=0;
  unsigned* poolz=0;

  auto plan = [&](int G)->size_t{
    size_t off = 0;
    auto A = [&](size_t bytes)->char*{
      char* p = (char*)d_ws + off;
      off += (bytes + 255) & ~(size_t)255;
      return p;
    };
    accb  = (float*)A((size_t)N_NODES*512*4);
    skipb = (bf16*) A((size_t)N_NODES*512*2);
    h1    = (bf16*) A((size_t)N_NODES*512*2);
    h2    = (bf16*) A((size_t)N_NODES*256*2);
    h3    = (bf16*) A((size_t)N_NODES*128*2);
    src   = (int*)  A((size_t)N_EDGES*4);
    dst   = (int*)  A((size_t)N_EDGES*4);
    bat   = (int*)  A((size_t)N_NODES*4);
    cnt   = (int*)  A((size_t)N_NODES*4);
    row_ptr=(int*)  A((size_t)(N_NODES+1)*4);
    fillp = (int*)  A((size_t)N_NODES*4);
    eids  = (int*)  A((size_t)N_EDGES*4);
    flag  = (int*)  A(256);
    gate  = (float*)A((size_t)N_NODES*4);
    poolz = (unsigned*)A((size_t)(64 + 64 + 64*128)*4);
    // normalized bf16 copies of all float inputs
    for (int t = 0; t < 29; ++t){
      int ix = FIDX[t];
      cv[ix] = (bf16*)A((size_t)in_sizes[ix]*2);
    }
    // transposed weights
    static const int wdim[12][2] = {{128,4096},{128,4096},{128,4096},{128,512},
                                    {512,2048},{512,2048},{512,2048},{512,256},
                                    {256,1024},{256,1024},{256,1024},{256,128}};
    for (int t = 0; t < 12; ++t)
      wt[t] = (bf16*)A((size_t)wdim[t][0]*wdim[t][1]*2);
    Qg = (bf16*)A((size_t)N_NODES*G*512*2);
    Kg = (bf16*)A((size_t)N_NODES*G*512*2);
    Vg = (bf16*)A((size_t)N_NODES*G*512*2);
    scores = (float*)A((size_t)N_EDGES*G*4);
    return off;
  };

  int G = 8;
  while (G > 1 && plan(G) > ws_size) G >>= 1;
  if (plan(G) > ws_size) return;   // doesn't fit even at G=1; output stays zero (visible failure)

  int* flagI = flag;       // int32-vs-int64 for indices
  int* flagF = flag + 1;   // fp32-vs-bf16 for float tensors
  unsigned* gmax = poolz;
  float*    gsum = (float*)(poolz + 64);
  float*    gacc = (float*)(poolz + 128);

  // ---- dtype detection + normalization ----
  zero_u32<<<1, 256, 0, stream>>>((unsigned*)flag, 2);
  {
    int nprobe = in_sizes[0] < 32768 ? in_sizes[0] : 32768;
    detect_f32_k<<<(nprobe + 255)/256, 256, 0, stream>>>((const unsigned short*)d_in[0], nprobe, flagF);
    detect_i64<<<16, 256, 0, stream>>>(ei, flagI);
  }
  for (int t = 0; t < 29; ++t){
    int ix = FIDX[t];
    int n = in_sizes[ix];
    to_bf16_k<<<(n + 255)/256, 256, 0, stream>>>(d_in[ix], cv[ix], n, flagF);
  }
  conv_idx<<<(N_EDGES + 255)/256, 256, 0, stream>>>(ei, braw, flagI, src, dst, bat);

  // ---- CSR ----
  zero_u32<<<(N_NODES + 255)/256, 256, 0, stream>>>((unsigned*)cnt, N_NODES);
  count_deg<<<(N_EDGES + 255)/256, 256, 0, stream>>>(dst, cnt);
  scan_deg<<<1, 1024, 0, stream>>>(cnt, row_ptr, fillp, N_NODES);
  fill_csr<<<(N_EDGES + 255)/256, 256, 0, stream>>>(dst, fillp, eids);

  // ---- weight transposes (inputs: normalized bf16 copies) ----
  {
    static const int wdim[12][2] = {{128,4096},{128,4096},{128,4096},{128,512},
                                    {512,2048},{512,2048},{512,2048},{512,256},
                                    {256,1024},{256,1024},{256,1024},{256,128}};
    static const int widx[12] = {3,5,7,9, 11,13,15,17, 19,21,23,25};
    for (int t = 0; t < 12; ++t)
      transpose_bf16<<<dim3(wdim[t][1]/32, wdim[t][0]/32), 256, 0, stream>>>(cv[widx[t]], wt[t], wdim[t][0], wdim[t][1]);
  }

  const int MT = (N_NODES + 127)/128;   // 79

  auto layer = [&](const bf16* hin, int Fin, int C,
                   const bf16* wtq, const bf16* bq,
                   const bf16* wtk, const bf16* bk,
                   const bf16* wtv, const bf16* bv,
                   const bf16* wts, const bf16* bs,
                   bf16* hout){
    int total = N_NODES * C;
    zero_u32<<<(total + 255)/256, 256, 0, stream>>>((unsigned*)accb, total);
    gemm_bias<<<dim3(C/128, MT), 256, 0, stream>>>(hin, wts, bs, skipb, N_NODES, C, Fin);
    float scale = 1.0f/sqrtf((float)C);
    int HG = 8 / G;
    int Ng = G * C;        // columns per head-group GEMM (>=128 for all layers)
    for (int g = 0; g < HG; ++g){
      size_t wofs = (size_t)g * Ng * Fin;
      gemm_bias<<<dim3(Ng/128, MT), 256, 0, stream>>>(hin, wtq + wofs, bq + (size_t)g*Ng, Qg, N_NODES, Ng, Fin);
      gemm_bias<<<dim3(Ng/128, MT), 256, 0, stream>>>(hin, wtk + wofs, bk + (size_t)g*Ng, Kg, N_NODES, Ng, Fin);
      gemm_bias<<<dim3(Ng/128, MT), 256, 0, stream>>>(hin, wtv + wofs, bv + (size_t)g*Ng, Vg, N_NODES, Ng, Fin);
      edge_scores<<<dim3((N_EDGES + 3)/4), 256, 0, stream>>>(Qg, Kg, src, dst, scores, G, C, scale);
      aggregate_acc<<<dim3(N_NODES), 64, 0, stream>>>(scores, Vg, row_ptr, eids, src, accb, G, C);
    }
    finalize_layer<<<(total + 255)/256, 256, 0, stream>>>(accb, skipb, hout, total);
  };

  layer(cv[0], 128, 512, wt[0], cv[4],  wt[1], cv[6],  wt[2], cv[8],  wt[3], cv[10], h1);
  layer(h1,    512, 256, wt[4], cv[12], wt[5], cv[14], wt[6], cv[16], wt[7], cv[18], h2);
  layer(h2,    256, 128, wt[8], cv[20], wt[9], cv[22], wt[10],cv[24], wt[11],cv[26], h3);

  // ---- global attention pooling + fc ----
  zero_u32<<<(64 + 64 + 64*128 + 255)/256, 256, 0, stream>>>(poolz, 64 + 64 + 64*128);
  gate_compute<<<(N_NODES + 3)/4, 256, 0, stream>>>(h3, cv[27], cv[28], gate);
  gate_max<<<(N_NODES + 255)/256, 256, 0, stream>>>(gate, bat, gmax);
  gate_expsum<<<(N_NODES + 255)/256, 256, 0, stream>>>(gate, bat, gmax, gsum);
  pool_weighted<<<(N_NODES + 3)/4, 256, 0, stream>>>(gate, gsum, bat, h3, gacc);
  final_fc<<<N_GRAPHS, 64, 0, stream>>>(gacc, cv[29], cv[30], d_out, flagF);
}

// Round 4
// 1258.261 us; speedup vs baseline: 1.8722x; 1.8722x over previous
//
#include <hip/hip_runtime.h>
#include <math.h>

typedef __bf16 bf16;
typedef __bf16 bf16x8 __attribute__((ext_vector_type(8)));
typedef float f32x4 __attribute__((ext_vector_type(4)));

#define N_NODES 10000
#define N_EDGES 80000
#define N_GRAPHS 64

template<int EPL> struct VecT;
template<> struct VecT<8>{ typedef bf16 type __attribute__((ext_vector_type(8))); };
template<> struct VecT<4>{ typedef bf16 type __attribute__((ext_vector_type(4))); };
template<> struct VecT<2>{ typedef bf16 type __attribute__((ext_vector_type(2))); };

__device__ inline unsigned f2ord(float f){
  unsigned u = __float_as_uint(f);
  return (u & 0x80000000u) ? ~u : (u | 0x80000000u);
}
__device__ inline float ord2f(unsigned u){
  return (u & 0x80000000u) ? __uint_as_float(u & 0x7fffffffu) : __uint_as_float(~u);
}

__global__ __launch_bounds__(256) void zero_u32(unsigned* __restrict__ p, int n){
  int i = blockIdx.x*256 + threadIdx.x;
  if (i < n) p[i] = 0u;
}

// ---- dtype detection: bf16 vs fp32 in the float-tensor buffers ----
__global__ __launch_bounds__(256) void detect_f32_k(const unsigned short* __restrict__ raw, int n,
                                                    int* __restrict__ flagF){
  int i = blockIdx.x*256 + threadIdx.x;
  if (i < n){
    unsigned e = (raw[i] >> 7) & 0xFFu;
    if (e >= 0xC0u) atomicOr(flagF, 1);
  }
}

// ---- batched conversion of 17 float tensors to bf16 (1 dispatch) ----
struct CvPack {
  const void* src[17];
  bf16* dst[17];
  int pre[18];
};
__global__ __launch_bounds__(256) void convert_all(CvPack p, const int* __restrict__ flagF){
  int gid = blockIdx.x*256 + threadIdx.x;
  if (gid >= p.pre[17]) return;
  int t = 0;
  while (gid >= p.pre[t+1]) ++t;
  int i = gid - p.pre[t];
  bool f = (*flagF != 0);
  p.dst[t][i] = f ? (bf16)((const float*)p.src[t])[i] : ((const bf16*)p.src[t])[i];
}

// edge_index may arrive as int32 or int64
__global__ __launch_bounds__(256) void detect_i64(const int* __restrict__ raw, int* __restrict__ flag){
  int i = blockIdx.x*256 + threadIdx.x;
  if (i < 4000 && raw[2*i+1] != 0) atomicOr(flag, 1);   // flag!=0 => int32
}

__global__ __launch_bounds__(256) void conv_idx(const int* __restrict__ ei_raw,
                                                const int* __restrict__ b_raw,
                                                const int* __restrict__ flag,
                                                int* __restrict__ src, int* __restrict__ dst,
                                                int* __restrict__ bat){
  int i = blockIdx.x*256 + threadIdx.x;
  bool i32 = (*flag != 0);
  if (i < N_EDGES){
    int s = i32 ? ei_raw[i]   : ei_raw[2*i];
    int d = i32 ? ei_raw[N_EDGES + i] : ei_raw[2*(N_EDGES + i)];
    src[i] = min(max(s, 0), N_NODES-1);
    dst[i] = min(max(d, 0), N_NODES-1);
  }
  if (i < N_NODES){
    int b = i32 ? b_raw[i] : b_raw[2*i];
    bat[i] = min(max(b, 0), N_GRAPHS-1);
  }
}

// ---------------- CSR build ----------------
__global__ __launch_bounds__(256) void count_deg(const int* __restrict__ dst, int* __restrict__ cnt){
  int e = blockIdx.x*256 + threadIdx.x;
  if (e < N_EDGES) atomicAdd(&cnt[dst[e]], 1);
}

__global__ __launch_bounds__(1024) void scan_deg(const int* __restrict__ cnt,
                                                 int* __restrict__ row_ptr,
                                                 int* __restrict__ fill, int N){
  __shared__ int sdata[1024];
  __shared__ int soff;
  int tid = threadIdx.x;
  if (tid == 0){ soff = 0; row_ptr[0] = 0; }
  __syncthreads();
  for (int base = 0; base < N; base += 1024){
    int i = base + tid;
    int v = (i < N) ? cnt[i] : 0;
    sdata[tid] = v;
    __syncthreads();
    for (int d = 1; d < 1024; d <<= 1){
      int t = (tid >= d) ? sdata[tid - d] : 0;
      __syncthreads();
      sdata[tid] += t;
      __syncthreads();
    }
    int incl  = sdata[tid] + soff;
    int total = sdata[1023];
    if (i < N){ row_ptr[i+1] = incl; fill[i] = incl - v; }
    __syncthreads();
    if (tid == 0) soff += total;
    __syncthreads();
  }
}

__global__ __launch_bounds__(256) void fill_csr(const int* __restrict__ dst,
                                                int* __restrict__ fill, int* __restrict__ eids){
  int e = blockIdx.x*256 + threadIdx.x;
  if (e < N_EDGES){
    int p = atomicAdd(&fill[dst[e]], 1);
    eids[p] = e;
  }
}

// ---------------- weight transpose  [K][N] -> [N][K], raw dtype branch ----------------
__global__ __launch_bounds__(256) void transpose_raw(const void* __restrict__ in, bf16* __restrict__ out,
                                                     int K, int N, const int* __restrict__ flagF){
  __shared__ bf16 t[32][33];
  bool f = (*flagF != 0);
  int bx = blockIdx.x;            // N/32
  int by = blockIdx.y;            // K/32
  int x = threadIdx.x & 31, y = threadIdx.x >> 5;
  #pragma unroll
  for (int i = 0; i < 4; ++i){
    int r = by*32 + y + i*8;
    size_t idx = (size_t)r*N + bx*32 + x;
    t[y + i*8][x] = f ? (bf16)((const float*)in)[idx] : ((const bf16*)in)[idx];
  }
  __syncthreads();
  #pragma unroll
  for (int i = 0; i < 4; ++i){
    int r = bx*32 + y + i*8;
    out[(size_t)r*K + by*32 + x] = t[x][y + i*8];
  }
}

// ---------------- GEMM: C[M][N] = A[M][K] @ Bt[N][K] + bias ----------------
__global__ __launch_bounds__(256)
void gemm_bias(const bf16* __restrict__ A, const bf16* __restrict__ Bt,
               const bf16* __restrict__ bias, bf16* __restrict__ Cout,
               int M, int N, int K)
{
  __shared__ bf16 As[128][72];
  __shared__ bf16 Bs[128][72];
  const int tid = threadIdx.x;
  const int lane = tid & 63;
  const int wave = tid >> 6;
  const int m0 = blockIdx.y * 128, n0 = blockIdx.x * 128;
  const int wm = (wave >> 1) * 64, wn = (wave & 1) * 64;
  const int l15 = lane & 15, l4 = lane >> 4;

  f32x4 acc[4][4] = {};

  for (int k0 = 0; k0 < K; k0 += 64){
    #pragma unroll
    for (int it = 0; it < 4; ++it){
      int v = tid + it*256;
      int row = v >> 3, colv = v & 7;
      bf16x8 av;
      #pragma unroll
      for (int j = 0; j < 8; ++j) av[j] = (bf16)0.0f;
      int grow = m0 + row;
      if (grow < M) av = *(const bf16x8*)(A + (size_t)grow*K + k0 + colv*8);
      *(bf16x8*)&As[row][colv*8] = av;
    }
    #pragma unroll
    for (int it = 0; it < 4; ++it){
      int v = tid + it*256;
      int row = v >> 3, colv = v & 7;
      bf16x8 bv = *(const bf16x8*)(Bt + (size_t)(n0 + row)*K + k0 + colv*8);
      *(bf16x8*)&Bs[row][colv*8] = bv;
    }
    __syncthreads();
    #pragma unroll
    for (int kt = 0; kt < 2; ++kt){
      bf16x8 af[4], bfr[4];
      #pragma unroll
      for (int mt = 0; mt < 4; ++mt) af[mt]  = *(const bf16x8*)&As[wm + mt*16 + l15][kt*32 + l4*8];
      #pragma unroll
      for (int nt = 0; nt < 4; ++nt) bfr[nt] = *(const bf16x8*)&Bs[wn + nt*16 + l15][kt*32 + l4*8];
      #pragma unroll
      for (int mt = 0; mt < 4; ++mt)
        #pragma unroll
        for (int nt = 0; nt < 4; ++nt)
          acc[mt][nt] = __builtin_amdgcn_mfma_f32_16x16x32_bf16(af[mt], bfr[nt], acc[mt][nt], 0, 0, 0);
    }
    __syncthreads();
  }

  #pragma unroll
  for (int nt = 0; nt < 4; ++nt){
    int col = n0 + wn + nt*16 + l15;
    float bv = (float)bias[col];
    #pragma unroll
    for (int mt = 0; mt < 4; ++mt){
      int rbase = m0 + wm + mt*16 + l4*4;
      #pragma unroll
      for (int r = 0; r < 4; ++r){
        int row = rbase + r;
        if (row < M) Cout[(size_t)row*N + col] = (bf16)(acc[mt][nt][r] + bv);
      }
    }
  }
}

// ---------------- fused per-node attention: scores + softmax + V-aggregate ----------------
// One block (4 waves) per node. Heads split across waves (h = wave, wave+4, ...).
// Q[n] row loaded once into registers; scores live in LDS; V gathered with vector loads.
template<int EPL>
__global__ __launch_bounds__(256)
void node_attn(const bf16* __restrict__ Q, const bf16* __restrict__ K, const bf16* __restrict__ V,
               const int* __restrict__ row_ptr, const int* __restrict__ eids, const int* __restrict__ srcv,
               float* __restrict__ accb, int G, float scale)
{
  constexpr int C = EPL*64;
  typedef typename VecT<EPL>::type vecb;
  __shared__ float sc[4][2][256];
  __shared__ float red[4][C];

  int n = blockIdx.x;
  int beg = row_ptr[n], deg = row_ptr[n+1] - beg;
  if (deg == 0) return;
  if (deg > 256) deg = 256;   // dataset: deg ~ Poisson(8); P(deg>256) ~ 0
  int wave = threadIdx.x >> 6, lane = threadIdx.x & 63;
  const size_t GC = (size_t)G*C;

  // load my Q slices (per assigned head) into registers
  float qreg[2][EPL];
  int nh = 0;
  for (int h = wave; h < G; h += 4, ++nh){
    vecb qv = *(const vecb*)(Q + (size_t)n*GC + (size_t)h*C + lane*EPL);
    #pragma unroll
    for (int k = 0; k < EPL; ++k) qreg[nh][k] = (float)qv[k];
  }

  // pass 1: scores -> LDS (scaled)
  for (int hl = 0; hl < nh; ++hl){
    int h = wave + hl*4;
    for (int i = 0; i < deg; ++i){
      int e = eids[beg + i];
      const bf16* kr = K + (size_t)srcv[e]*GC + (size_t)h*C + lane*EPL;
      vecb kv = *(const vecb*)kr;
      float s = 0.f;
      #pragma unroll
      for (int k = 0; k < EPL; ++k) s += qreg[hl][k] * (float)kv[k];
      #pragma unroll
      for (int o = 32; o; o >>= 1) s += __shfl_xor(s, o, 64);
      if (lane == 0) sc[wave][hl][i] = s * scale;
    }
  }

  // pass 2: softmax over LDS scores + weighted V gather, accumulate over my heads
  float acc[EPL];
  #pragma unroll
  for (int k = 0; k < EPL; ++k) acc[k] = 0.f;

  for (int hl = 0; hl < nh; ++hl){
    int h = wave + hl*4;
    float m = -3.4e38f;
    for (int i = lane; i < deg; i += 64) m = fmaxf(m, sc[wave][hl][i]);
    #pragma unroll
    for (int o = 32; o; o >>= 1) m = fmaxf(m, __shfl_xor(m, o, 64));
    float ss = 0.f;
    for (int i = lane; i < deg; i += 64) ss += __expf(sc[wave][hl][i] - m);
    #pragma unroll
    for (int o = 32; o; o >>= 1) ss += __shfl_xor(ss, o, 64);
    float inv = 1.f/(ss + 1e-16f);
    for (int i = 0; i < deg; ++i){
      int e = eids[beg + i];
      float w = __expf(sc[wave][hl][i] - m) * inv;
      const bf16* vr = V + (size_t)srcv[e]*GC + (size_t)h*C + lane*EPL;
      vecb vv = *(const vecb*)vr;
      #pragma unroll
      for (int k = 0; k < EPL; ++k) acc[k] += w * (float)vv[k];
    }
  }

  // cross-wave reduction
  #pragma unroll
  for (int k = 0; k < EPL; ++k) red[wave][lane*EPL + k] = acc[k];
  __syncthreads();
  for (int idx = threadIdx.x; idx < C; idx += 256){
    float s = red[0][idx] + red[1][idx] + red[2][idx] + red[3][idx];
    accb[(size_t)n*C + idx] += s;
  }
}

// ---------------- finalize: h = elu(acc/8 + skip) ----------------
__global__ __launch_bounds__(256) void finalize_layer(const float* __restrict__ accb, const bf16* __restrict__ skip,
                                                      bf16* __restrict__ hout, int total){
  int i = blockIdx.x*256 + threadIdx.x;
  if (i < total){
    float v = accb[i]*0.125f + (float)skip[i];
    v = (v > 0.f) ? v : (__expf(v) - 1.f);
    hout[i] = (bf16)v;
  }
}

// ---------------- pooling ----------------
__global__ __launch_bounds__(256) void gate_compute(const bf16* __restrict__ h, const bf16* __restrict__ wg,
                                                    const bf16* __restrict__ bg, float* __restrict__ gate){
  int n = blockIdx.x*4 + (threadIdx.x >> 6);
  if (n >= N_NODES) return;
  int lane = threadIdx.x & 63;
  const bf16* hr = h + (size_t)n*128;
  float s = (float)hr[lane]*(float)wg[lane] + (float)hr[64+lane]*(float)wg[64+lane];
  #pragma unroll
  for (int o = 32; o; o >>= 1) s += __shfl_xor(s, o, 64);
  if (lane == 0) gate[n] = s + (float)bg[0];
}

__global__ __launch_bounds__(256) void gate_max(const float* __restrict__ gate, const int* __restrict__ bat,
                                                unsigned* __restrict__ gmax){
  int n = blockIdx.x*256 + threadIdx.x;
  if (n < N_NODES) atomicMax(&gmax[bat[n]], f2ord(gate[n]));
}

__global__ __launch_bounds__(256) void gate_expsum(float* __restrict__ gate, const int* __restrict__ bat,
                                                   const unsigned* __restrict__ gmax, float* __restrict__ gsum){
  int n = blockIdx.x*256 + threadIdx.x;
  if (n < N_NODES){
    float e = __expf(gate[n] - ord2f(gmax[bat[n]]));
    gate[n] = e;
    atomicAdd(&gsum[bat[n]], e);
  }
}

__global__ __launch_bounds__(256) void pool_weighted(const float* __restrict__ gate, const float* __restrict__ gsum,
                                                     const int* __restrict__ bat, const bf16* __restrict__ h,
                                                     float* __restrict__ gacc){
  int n = blockIdx.x*4 + (threadIdx.x >> 6);
  if (n >= N_NODES) return;
  int lane = threadIdx.x & 63;
  int b = bat[n];
  float w = gate[n]/(gsum[b] + 1e-16f);
  atomicAdd(&gacc[b*128 + lane],      w*(float)h[(size_t)n*128 + lane]);
  atomicAdd(&gacc[b*128 + 64 + lane], w*(float)h[(size_t)n*128 + 64 + lane]);
}

__global__ __launch_bounds__(64) void final_fc(const float* __restrict__ gacc, const bf16* __restrict__ wfc,
                                               const bf16* __restrict__ bfc, void* __restrict__ out,
                                               const int* __restrict__ flagF){
  int g = blockIdx.x;
  int o = threadIdx.x;
  if (o < 10){
    float s = (float)bfc[o];
    for (int c = 0; c < 128; ++c) s += gacc[g*128 + c]*(float)wfc[c*10 + o];
    if (*flagF) ((float*)out)[(size_t)g*10 + o] = s;
    else        ((bf16*)out)[(size_t)g*10 + o]  = (bf16)s;
  }
}

extern "C" void kernel_launch(void* const* d_in, const int* in_sizes, int n_in,
                              void* d_out, int out_size, void* d_ws, size_t ws_size,
                              hipStream_t stream)
{
  const int* ei   = (const int*)d_in[1];
  const int* braw = (const int*)d_in[2];

  // float tensors needing bf16 copies: x, 12 biases, w_g, b_g, w_fc, b_fc
  static const int CIDX[17] = {0,4,6,8,10,12,14,16,18,20,22,24,26,27,28,29,30};
  static const int wdim[12][2] = {{128,4096},{128,4096},{128,4096},{128,512},
                                  {512,2048},{512,2048},{512,2048},{512,256},
                                  {256,1024},{256,1024},{256,1024},{256,128}};
  static const int widx[12] = {3,5,7,9, 11,13,15,17, 19,21,23,25};

  bf16 *Qg=0, *Kg=0, *Vg=0, *skipb=0, *h1=0, *h2=0, *h3=0;
  bf16 *wt[12];
  bf16 *cv[31];
  float *accb=0, *gate=0;
  int *src=0,*dst=0,*bat=0,*cnt=0,*row_ptr=0,*fillp=0,*eids=0,*flag=0;
  unsigned* poolz=0;

  auto plan = [&](int G)->size_t{
    size_t off = 0;
    auto A = [&](size_t bytes)->char*{
      char* p = (char*)d_ws + off;
      off += (bytes + 255) & ~(size_t)255;
      return p;
    };
    accb  = (float*)A((size_t)N_NODES*512*4);
    skipb = (bf16*) A((size_t)N_NODES*512*2);
    h1    = (bf16*) A((size_t)N_NODES*512*2);
    h2    = (bf16*) A((size_t)N_NODES*256*2);
    h3    = (bf16*) A((size_t)N_NODES*128*2);
    src   = (int*)  A((size_t)N_EDGES*4);
    dst   = (int*)  A((size_t)N_EDGES*4);
    bat   = (int*)  A((size_t)N_NODES*4);
    cnt   = (int*)  A((size_t)N_NODES*4);
    row_ptr=(int*)  A((size_t)(N_NODES+1)*4);
    fillp = (int*)  A((size_t)N_NODES*4);
    eids  = (int*)  A((size_t)N_EDGES*4);
    flag  = (int*)  A(256);
    gate  = (float*)A((size_t)N_NODES*4);
    poolz = (unsigned*)A((size_t)(64 + 64 + 64*128)*4);
    for (int t = 0; t < 17; ++t)
      cv[CIDX[t]] = (bf16*)A((size_t)in_sizes[CIDX[t]]*2);
    for (int t = 0; t < 12; ++t)
      wt[t] = (bf16*)A((size_t)wdim[t][0]*wdim[t][1]*2);
    Qg = (bf16*)A((size_t)N_NODES*G*512*2);
    Kg = (bf16*)A((size_t)N_NODES*G*512*2);
    Vg = (bf16*)A((size_t)N_NODES*G*512*2);
    return off;
  };

  int G = 8;
  while (G > 1 && plan(G) > ws_size) G >>= 1;
  if (plan(G) > ws_size) return;   // doesn't fit even at G=1; output stays zero (visible failure)

  int* flagI = flag;
  int* flagF = flag + 1;
  unsigned* gmax = poolz;
  float*    gsum = (float*)(poolz + 64);
  float*    gacc = (float*)(poolz + 128);

  // ---- dtype detection ----
  zero_u32<<<1, 256, 0, stream>>>((unsigned*)flag, 2);
  {
    int nprobe = in_sizes[0] < 32768 ? in_sizes[0] : 32768;
    detect_f32_k<<<(nprobe + 255)/256, 256, 0, stream>>>((const unsigned short*)d_in[0], nprobe, flagF);
    detect_i64<<<16, 256, 0, stream>>>(ei, flagI);
  }
  // ---- batched conversion (x, biases, gate/fc params) ----
  {
    CvPack p;
    int tot = 0;
    for (int t = 0; t < 17; ++t){
      p.src[t] = d_in[CIDX[t]];
      p.dst[t] = cv[CIDX[t]];
      p.pre[t] = tot;
      tot += in_sizes[CIDX[t]];
    }
    p.pre[17] = tot;
    convert_all<<<(tot + 255)/256, 256, 0, stream>>>(p, flagF);
  }
  conv_idx<<<(N_EDGES + 255)/256, 256, 0, stream>>>(ei, braw, flagI, src, dst, bat);

  // ---- CSR ----
  zero_u32<<<(N_NODES + 255)/256, 256, 0, stream>>>((unsigned*)cnt, N_NODES);
  count_deg<<<(N_EDGES + 255)/256, 256, 0, stream>>>(dst, cnt);
  scan_deg<<<1, 1024, 0, stream>>>(cnt, row_ptr, fillp, N_NODES);
  fill_csr<<<(N_EDGES + 255)/256, 256, 0, stream>>>(dst, fillp, eids);

  // ---- weight transposes (read raw, dtype branch inside) ----
  for (int t = 0; t < 12; ++t)
    transpose_raw<<<dim3(wdim[t][1]/32, wdim[t][0]/32), 256, 0, stream>>>(d_in[widx[t]], wt[t], wdim[t][0], wdim[t][1], flagF);

  const int MT = (N_NODES + 127)/128;   // 79

  auto layer = [&](const bf16* hin, int Fin, int C,
                   const bf16* wtq, const bf16* bq,
                   const bf16* wtk, const bf16* bk,
                   const bf16* wtv, const bf16* bv,
                   const bf16* wts, const bf16* bs,
                   bf16* hout){
    int total = N_NODES * C;
    zero_u32<<<(total + 255)/256, 256, 0, stream>>>((unsigned*)accb, total);
    gemm_bias<<<dim3(C/128, MT), 256, 0, stream>>>(hin, wts, bs, skipb, N_NODES, C, Fin);
    float scale = 1.0f/sqrtf((float)C);
    int HG = 8 / G;
    int Ng = G * C;
    for (int g = 0; g < HG; ++g){
      size_t wofs = (size_t)g * Ng * Fin;
      gemm_bias<<<dim3(Ng/128, MT), 256, 0, stream>>>(hin, wtq + wofs, bq + (size_t)g*Ng, Qg, N_NODES, Ng, Fin);
      gemm_bias<<<dim3(Ng/128, MT), 256, 0, stream>>>(hin, wtk + wofs, bk + (size_t)g*Ng, Kg, N_NODES, Ng, Fin);
      gemm_bias<<<dim3(Ng/128, MT), 256, 0, stream>>>(hin, wtv + wofs, bv + (size_t)g*Ng, Vg, N_NODES, Ng, Fin);
      if (C == 512)      node_attn<8><<<N_NODES, 256, 0, stream>>>(Qg, Kg, Vg, row_ptr, eids, src, accb, G, scale);
      else if (C == 256) node_attn<4><<<N_NODES, 256, 0, stream>>>(Qg, Kg, Vg, row_ptr, eids, src, accb, G, scale);
      else               node_attn<2><<<N_NODES, 256, 0, stream>>>(Qg, Kg, Vg, row_ptr, eids, src, accb, G, scale);
    }
    finalize_layer<<<(total + 255)/256, 256, 0, stream>>>(accb, skipb, hout, total);
  };

  layer(cv[0], 128, 512, wt[0], cv[4],  wt[1], cv[6],  wt[2], cv[8],  wt[3], cv[10], h1);
  layer(h1,    512, 256, wt[4], cv[12], wt[5], cv[14], wt[6], cv[16], wt[7], cv[18], h2);
  layer(h2,    256, 128, wt[8], cv[20], wt[9], cv[22], wt[10],cv[24], wt[11],cv[26], h3);

  // ---- global attention pooling + fc ----
  zero_u32<<<(64 + 64 + 64*128 + 255)/256, 256, 0, stream>>>(poolz, 64 + 64 + 64*128);
  gate_compute<<<(N_NODES + 3)/4, 256, 0, stream>>>(h3, cv[27], cv[28], gate);
  gate_max<<<(N_NODES + 255)/256, 256, 0, stream>>>(gate, bat, gmax);
  gate_expsum<<<(N_NODES + 255)/256, 256, 0, stream>>>(gate, bat, gmax, gsum);
  pool_weighted<<<(N_NODES + 3)/4, 256, 0, stream>>>(gate, gsum, bat, h3, gacc);
  final_fc<<<N_GRAPHS, 64, 0, stream>>>(gacc, cv[29], cv[30], d_out, flagF);
}

// Round 6
// 1164.332 us; speedup vs baseline: 2.0232x; 1.0807x over previous
//
#include <hip/hip_runtime.h>
#include <math.h>

typedef __bf16 bf16;
typedef __bf16 bf16x8 __attribute__((ext_vector_type(8)));
typedef float f32x4 __attribute__((ext_vector_type(4)));

#define N_NODES 10000
#define N_EDGES 80000
#define N_GRAPHS 64

template<int EPL> struct VecT;
template<> struct VecT<8>{ typedef bf16 type __attribute__((ext_vector_type(8))); };
template<> struct VecT<4>{ typedef bf16 type __attribute__((ext_vector_type(4))); };
template<> struct VecT<2>{ typedef bf16 type __attribute__((ext_vector_type(2))); };

__device__ inline unsigned f2ord(float f){
  unsigned u = __float_as_uint(f);
  return (u & 0x80000000u) ? ~u : (u | 0x80000000u);
}
__device__ inline float ord2f(unsigned u){
  return (u & 0x80000000u) ? __uint_as_float(u & 0x7fffffffu) : __uint_as_float(~u);
}

// async global->LDS, 16B per lane; LDS dest = base + lane*16 (wave-uniform base)
__device__ inline void gload_lds16(const bf16* g, bf16* l){
  __builtin_amdgcn_global_load_lds(
      (const __attribute__((address_space(1))) unsigned int*)g,
      (__attribute__((address_space(3))) unsigned int*)l, 16, 0, 0);
}

__global__ __launch_bounds__(256) void zero_u32(unsigned* __restrict__ p, int n){
  int i = blockIdx.x*256 + threadIdx.x;
  if (i < n) p[i] = 0u;
}

__global__ __launch_bounds__(256) void detect_f32_k(const unsigned short* __restrict__ raw, int n,
                                                    int* __restrict__ flagF){
  int i = blockIdx.x*256 + threadIdx.x;
  if (i < n){
    unsigned e = (raw[i] >> 7) & 0xFFu;
    if (e >= 0xC0u) atomicOr(flagF, 1);
  }
}

// ---- batched conversion of 5 small float tensors to bf16 ----
struct CvPack {
  const void* src[5];
  bf16* dst[5];
  int pre[6];
};
__global__ __launch_bounds__(256) void convert_all(CvPack p, const int* __restrict__ flagF){
  int gid = blockIdx.x*256 + threadIdx.x;
  if (gid >= p.pre[5]) return;
  int t = 0;
  while (gid >= p.pre[t+1]) ++t;
  int i = gid - p.pre[t];
  bool f = (*flagF != 0);
  p.dst[t][i] = f ? (bf16)((const float*)p.src[t])[i] : ((const bf16*)p.src[t])[i];
}

__global__ __launch_bounds__(256) void detect_i64(const int* __restrict__ raw, int* __restrict__ flag){
  int i = blockIdx.x*256 + threadIdx.x;
  if (i < 4000 && raw[2*i+1] != 0) atomicOr(flag, 1);   // flag!=0 => int32
}

__global__ __launch_bounds__(256) void conv_idx(const int* __restrict__ ei_raw,
                                                const int* __restrict__ b_raw,
                                                const int* __restrict__ flag,
                                                int* __restrict__ src, int* __restrict__ dst,
                                                int* __restrict__ bat){
  int i = blockIdx.x*256 + threadIdx.x;
  bool i32 = (*flag != 0);
  if (i < N_EDGES){
    int s = i32 ? ei_raw[i]   : ei_raw[2*i];
    int d = i32 ? ei_raw[N_EDGES + i] : ei_raw[2*(N_EDGES + i)];
    src[i] = min(max(s, 0), N_NODES-1);
    dst[i] = min(max(d, 0), N_NODES-1);
  }
  if (i < N_NODES){
    int b = i32 ? b_raw[i] : b_raw[2*i];
    bat[i] = min(max(b, 0), N_GRAPHS-1);
  }
}

// ---------------- CSR build ----------------
__global__ __launch_bounds__(256) void count_deg(const int* __restrict__ dst, int* __restrict__ cnt){
  int e = blockIdx.x*256 + threadIdx.x;
  if (e < N_EDGES) atomicAdd(&cnt[dst[e]], 1);
}

__global__ __launch_bounds__(1024) void scan_deg(const int* __restrict__ cnt,
                                                 int* __restrict__ row_ptr,
                                                 int* __restrict__ fill, int N){
  __shared__ int sdata[1024];
  __shared__ int soff;
  int tid = threadIdx.x;
  if (tid == 0){ soff = 0; row_ptr[0] = 0; }
  __syncthreads();
  for (int base = 0; base < N; base += 1024){
    int i = base + tid;
    int v = (i < N) ? cnt[i] : 0;
    sdata[tid] = v;
    __syncthreads();
    for (int d = 1; d < 1024; d <<= 1){
      int t = (tid >= d) ? sdata[tid - d] : 0;
      __syncthreads();
      sdata[tid] += t;
      __syncthreads();
    }
    int incl  = sdata[tid] + soff;
    int total = sdata[1023];
    if (i < N){ row_ptr[i+1] = incl; fill[i] = incl - v; }
    __syncthreads();
    if (tid == 0) soff += total;
    __syncthreads();
  }
}

__global__ __launch_bounds__(256) void fill_csr(const int* __restrict__ dst,
                                                int* __restrict__ fill, int* __restrict__ eids){
  int e = blockIdx.x*256 + threadIdx.x;
  if (e < N_EDGES){
    int p = atomicAdd(&fill[dst[e]], 1);
    eids[p] = e;
  }
}

// ---------------- grouped concat weight transpose ----------------
// out rows (25C total): [g*(3*GH*C) + {0:q,1:k,2:v}*GH*C + hh*C + cc] for head h=g*GH+hh,
// then [24C,25C) = skip. out[row][Fin] = w[Fin][col].
__global__ __launch_bounds__(256)
void transpose_grp(const void* __restrict__ wq, const void* __restrict__ wk,
                   const void* __restrict__ wv, const void* __restrict__ wsS,
                   bf16* __restrict__ out, int Fin, int C, int GH,
                   const int* __restrict__ flagF){
  __shared__ bf16 t[32][33];
  bool f = (*flagF != 0);
  int r0 = blockIdx.x * 32;     // output-row tile base (32-aligned; C>=128 so tile never straddles sections)
  const void* src; int colbase; int nstride;
  if (r0 < 24*C){
    int gw = 3*GH*C;
    int g = r0 / gw, rem = r0 - g*gw;
    int sec = rem / (GH*C);
    int hh  = (rem - sec*GH*C) / C;
    int cc  = rem % C;
    int h = g*GH + hh;
    src = (sec == 0) ? wq : (sec == 1) ? wk : wv;
    colbase = h*C + cc;
    nstride = 8*C;
  } else {
    src = wsS; colbase = r0 - 24*C; nstride = C;
  }
  int by = blockIdx.y;          // Fin tile
  int x = threadIdx.x & 31, y = threadIdx.x >> 5;
  #pragma unroll
  for (int i = 0; i < 4; ++i){
    int r = by*32 + y + i*8;    // input (Fin) row
    size_t idx = (size_t)r*nstride + colbase + x;
    t[y + i*8][x] = f ? (bf16)((const float*)src)[idx] : ((const bf16*)src)[idx];
  }
  __syncthreads();
  #pragma unroll
  for (int i = 0; i < 4; ++i){
    int orow = r0 + y + i*8;
    out[(size_t)orow*Fin + by*32 + x] = t[x][y + i*8];
  }
}

// grouped bias arrange: bcat[25C] in the same ordering
__global__ __launch_bounds__(256)
void bias_arrange(const void* __restrict__ bq, const void* __restrict__ bk,
                  const void* __restrict__ bv, const void* __restrict__ bs,
                  bf16* __restrict__ out, int C, int GH, const int* __restrict__ flagF){
  int j = blockIdx.x*256 + threadIdx.x;
  if (j >= 25*C) return;
  bool f = (*flagF != 0);
  const void* src; int idx;
  if (j < 24*C){
    int gw = 3*GH*C;
    int g = j / gw, rem = j - g*gw;
    int sec = rem / (GH*C);
    int hh  = (rem - sec*GH*C) / C;
    int cc  = rem % C;
    int h = g*GH + hh;
    src = (sec == 0) ? bq : (sec == 1) ? bk : bv;
    idx = h*C + cc;
  } else { src = bs; idx = j - 24*C; }
  out[j] = f ? (bf16)((const float*)src)[idx] : ((const bf16*)src)[idx];
}

// ---------------- GEMM: C[M][N] = A[M][K] @ Bt[N][K] + bias ----------------
// global_load_lds width-16 staging with XOR-swizzled LDS (phys chunk = logical ^ (row&7)).
__global__ __launch_bounds__(256)
void gemm_bias(const bf16* __restrict__ A, const bf16* __restrict__ Bt,
               const bf16* __restrict__ bias, bf16* __restrict__ Cout,
               int M, int N, int K)
{
  __shared__ bf16 As[128*64];
  __shared__ bf16 Bs[128*64];
  const int tid = threadIdx.x;
  const int lane = tid & 63;
  const int wave = tid >> 6;
  const int m0 = blockIdx.y * 128, n0 = blockIdx.x * 128;
  const int wm = (wave >> 1) * 64, wn = (wave & 1) * 64;
  const int l15 = lane & 15, l4 = lane >> 4;
  const int srow = lane >> 3;       // 0..7 within the wave's 8-row group
  const int schunk = lane & 7;      // physical chunk this lane fills

  f32x4 acc[4][4] = {};

  for (int k0 = 0; k0 < K; k0 += 64){
    #pragma unroll
    for (int j = 0; j < 4; ++j){
      int r0 = (wave*4 + j)*8;
      int r  = r0 + srow;
      int gc = schunk ^ (r & 7);    // logical chunk fetched into this physical slot
      int ga = m0 + r; if (ga >= M) ga = M-1;   // clamp: dup row, epilogue guards store
      gload_lds16(A  + (size_t)ga*K        + k0 + gc*8, As + r0*64);
      gload_lds16(Bt + (size_t)(n0 + r)*K  + k0 + gc*8, Bs + r0*64);
    }
    __syncthreads();
    #pragma unroll
    for (int kt = 0; kt < 2; ++kt){
      bf16x8 af[4], bfr[4];
      #pragma unroll
      for (int mt = 0; mt < 4; ++mt){
        int row = wm + mt*16 + l15;
        int p = (kt*4 + l4) ^ (l15 & 7);
        af[mt] = *(const bf16x8*)(As + row*64 + p*8);
      }
      #pragma unroll
      for (int nt = 0; nt < 4; ++nt){
        int row = wn + nt*16 + l15;
        int p = (kt*4 + l4) ^ (l15 & 7);
        bfr[nt] = *(const bf16x8*)(Bs + row*64 + p*8);
      }
      #pragma unroll
      for (int mt = 0; mt < 4; ++mt)
        #pragma unroll
        for (int nt = 0; nt < 4; ++nt)
          acc[mt][nt] = __builtin_amdgcn_mfma_f32_16x16x32_bf16(af[mt], bfr[nt], acc[mt][nt], 0, 0, 0);
    }
    __syncthreads();
  }

  #pragma unroll
  for (int nt = 0; nt < 4; ++nt){
    int col = n0 + wn + nt*16 + l15;
    float bv = (float)bias[col];
    #pragma unroll
    for (int mt = 0; mt < 4; ++mt){
      int rbase = m0 + wm + mt*16 + l4*4;
      #pragma unroll
      for (int r = 0; r < 4; ++r){
        int row = rbase + r;
        if (row < M) Cout[(size_t)row*N + col] = (bf16)(acc[mt][nt][r] + bv);
      }
    }
  }
}

// ---------------- fused per-node attention for one head group (online softmax) ----------------
// QKVg row layout: [q(GH*C) | k(GH*C) | v(GH*C)], stride S=3*GH*C.
// One block per node, 4 waves; wave owns heads hh = wave, wave+4 (< GH).
template<int EPL>
__global__ __launch_bounds__(256)
void node_attn_g(const bf16* __restrict__ QKVg, int GH,
                 const int* __restrict__ row_ptr, const int* __restrict__ eids,
                 const int* __restrict__ srcv, float* __restrict__ accb, float scale)
{
  constexpr int C = EPL*64;
  typedef typename VecT<EPL>::type vecb;
  __shared__ int sSrc[256];
  __shared__ float red[4][C];

  const int S = 3*GH*C;
  int n = blockIdx.x;
  int beg = row_ptr[n], deg = row_ptr[n+1] - beg;
  int wave = threadIdx.x >> 6, lane = threadIdx.x & 63;

  float qreg[2][EPL], acc[2][EPL], m[2], l[2];
  int nh = 0;
  for (int hh = wave; hh < GH; hh += 4, ++nh){
    vecb qv = *(const vecb*)(QKVg + (size_t)n*S + hh*C + lane*EPL);
    #pragma unroll
    for (int k = 0; k < EPL; ++k){ qreg[nh][k] = (float)qv[k]; acc[nh][k] = 0.f; }
    m[nh] = -3.4e38f; l[nh] = 0.f;
  }

  for (int c0 = 0; c0 < deg; c0 += 256){
    int cn = min(256, deg - c0);
    __syncthreads();
    if (threadIdx.x < cn) sSrc[threadIdx.x] = srcv[eids[beg + c0 + threadIdx.x]];
    __syncthreads();
    for (int i = 0; i < cn; ++i){
      const bf16* base = QKVg + (size_t)sSrc[i]*S;
      int hl = 0;
      for (int hh = wave; hh < GH; hh += 4, ++hl){
        vecb kv = *(const vecb*)(base + GH*C + hh*C + lane*EPL);
        float s = 0.f;
        #pragma unroll
        for (int k = 0; k < EPL; ++k) s += qreg[hl][k] * (float)kv[k];
        #pragma unroll
        for (int o = 32; o; o >>= 1) s += __shfl_xor(s, o, 64);
        s *= scale;
        float nm = fmaxf(m[hl], s);
        float al = __expf(m[hl] - nm);
        float w  = __expf(s - nm);
        l[hl] = l[hl]*al + w;
        vecb vv = *(const vecb*)(base + 2*GH*C + hh*C + lane*EPL);
        #pragma unroll
        for (int k = 0; k < EPL; ++k) acc[hl][k] = acc[hl][k]*al + w*(float)vv[k];
        m[hl] = nm;
      }
    }
  }

  float outp[EPL];
  #pragma unroll
  for (int k = 0; k < EPL; ++k) outp[k] = 0.f;
  if (deg > 0){
    for (int hl = 0; hl < nh; ++hl){
      float inv = 1.f/(l[hl] + 1e-16f);
      #pragma unroll
      for (int k = 0; k < EPL; ++k) outp[k] += acc[hl][k]*inv;
    }
  }
  #pragma unroll
  for (int k = 0; k < EPL; ++k) red[wave][lane*EPL + k] = outp[k];
  __syncthreads();
  for (int idx = threadIdx.x; idx < C; idx += 256){
    float sm = red[0][idx] + red[1][idx] + red[2][idx] + red[3][idx];
    accb[(size_t)n*C + idx] += sm;
  }
}

// ---------------- finalize: h = elu(acc/8 + skip) ----------------
__global__ __launch_bounds__(256) void finalize_layer(const float* __restrict__ accb, const bf16* __restrict__ skip,
                                                      bf16* __restrict__ hout, int total){
  int i = blockIdx.x*256 + threadIdx.x;
  if (i < total){
    float v = accb[i]*0.125f + (float)skip[i];
    v = (v > 0.f) ? v : (__expf(v) - 1.f);
    hout[i] = (bf16)v;
  }
}

// ---------------- pooling ----------------
__global__ __launch_bounds__(256) void gate_compute(const bf16* __restrict__ h, const bf16* __restrict__ wg,
                                                    const bf16* __restrict__ bg, float* __restrict__ gate){
  int n = blockIdx.x*4 + (threadIdx.x >> 6);
  if (n >= N_NODES) return;
  int lane = threadIdx.x & 63;
  const bf16* hr = h + (size_t)n*128;
  float s = (float)hr[lane]*(float)wg[lane] + (float)hr[64+lane]*(float)wg[64+lane];
  #pragma unroll
  for (int o = 32; o; o >>= 1) s += __shfl_xor(s, o, 64);
  if (lane == 0) gate[n] = s + (float)bg[0];
}

__global__ __launch_bounds__(256) void gate_max(const float* __restrict__ gate, const int* __restrict__ bat,
                                                unsigned* __restrict__ gmax){
  int n = blockIdx.x*256 + threadIdx.x;
  if (n < N_NODES) atomicMax(&gmax[bat[n]], f2ord(gate[n]));
}

__global__ __launch_bounds__(256) void gate_expsum(float* __restrict__ gate, const int* __restrict__ bat,
                                                   const unsigned* __restrict__ gmax, float* __restrict__ gsum){
  int n = blockIdx.x*256 + threadIdx.x;
  if (n < N_NODES){
    float e = __expf(gate[n] - ord2f(gmax[bat[n]]));
    gate[n] = e;
    atomicAdd(&gsum[bat[n]], e);
  }
}

__global__ __launch_bounds__(256) void pool_weighted(const float* __restrict__ gate, const float* __restrict__ gsum,
                                                     const int* __restrict__ bat, const bf16* __restrict__ h,
                                                     float* __restrict__ gacc){
  int n = blockIdx.x*4 + (threadIdx.x >> 6);
  if (n >= N_NODES) return;
  int lane = threadIdx.x & 63;
  int b = bat[n];
  float w = gate[n]/(gsum[b] + 1e-16f);
  atomicAdd(&gacc[b*128 + lane],      w*(float)h[(size_t)n*128 + lane]);
  atomicAdd(&gacc[b*128 + 64 + lane], w*(float)h[(size_t)n*128 + 64 + lane]);
}

__global__ __launch_bounds__(64) void final_fc(const float* __restrict__ gacc, const bf16* __restrict__ wfc,
                                               const bf16* __restrict__ bfc, void* __restrict__ out,
                                               const int* __restrict__ flagF){
  int g = blockIdx.x;
  int o = threadIdx.x;
  if (o < 10){
    float s = (float)bfc[o];
    for (int c = 0; c < 128; ++c) s += gacc[g*128 + c]*(float)wfc[c*10 + o];
    if (*flagF) ((float*)out)[(size_t)g*10 + o] = s;
    else        ((bf16*)out)[(size_t)g*10 + o]  = (bf16)s;
  }
}

extern "C" void kernel_launch(void* const* d_in, const int* in_sizes, int n_in,
                              void* d_out, int out_size, void* d_ws, size_t ws_size,
                              hipStream_t stream)
{
  const int* ei   = (const int*)d_in[1];
  const int* braw = (const int*)d_in[2];

  bf16 *QKVg=0, *skipb=0, *h1=0, *h2=0, *h3=0, *cvx=0;
  bf16 *wcat1=0,*wcat2=0,*wcat3=0,*bcat1=0,*bcat2=0,*bcat3=0;
  bf16 *cwg=0,*cbg=0,*cwfc=0,*cbfc=0;
  float *accb=0,*gate=0;
  int *src=0,*dst=0,*bat=0,*cnt=0,*row_ptr=0,*fillp=0,*eids=0,*flag=0;
  unsigned* poolz=0;

  auto plan = [&](int GH)->size_t{
    size_t off = 0;
    auto A = [&](size_t bytes)->char*{
      char* p = (char*)d_ws + off;
      off += (bytes + 255) & ~(size_t)255;
      return p;
    };
    QKVg = (bf16*)A((size_t)N_NODES*3*GH*512*2);
    accb = (float*)A((size_t)N_NODES*512*4);
    skipb= (bf16*) A((size_t)N_NODES*512*2);
    h1   = (bf16*) A((size_t)N_NODES*512*2);
    h2   = (bf16*) A((size_t)N_NODES*256*2);
    h3   = (bf16*) A((size_t)N_NODES*128*2);
    cvx  = (bf16*) A((size_t)N_NODES*128*2);
    wcat1= (bf16*) A((size_t)12800*128*2);
    wcat2= (bf16*) A((size_t)6400*512*2);
    wcat3= (bf16*) A((size_t)3200*256*2);
    bcat1= (bf16*) A(12800*2);
    bcat2= (bf16*) A(6400*2);
    bcat3= (bf16*) A(3200*2);
    cwg  = (bf16*) A(128*2);
    cbg  = (bf16*) A(2*2);
    cwfc = (bf16*) A(1280*2);
    cbfc = (bf16*) A(10*2);
    src  = (int*)  A((size_t)N_EDGES*4);
    dst  = (int*)  A((size_t)N_EDGES*4);
    bat  = (int*)  A((size_t)N_NODES*4);
    cnt  = (int*)  A((size_t)N_NODES*4);
    row_ptr=(int*) A((size_t)(N_NODES+1)*4);
    fillp= (int*)  A((size_t)N_NODES*4);
    eids = (int*)  A((size_t)N_EDGES*4);
    flag = (int*)  A(256);
    gate = (float*)A((size_t)N_NODES*4);
    poolz= (unsigned*)A((size_t)(64 + 64 + 64*128)*4);
    return off;
  };

  int GH = 8;
  while (GH > 1 && plan(GH) > ws_size) GH >>= 1;
  if (plan(GH) > ws_size) return;   // even floor plan (~95 MB) doesn't fit; visible failure
  const int HG = 8 / GH;

  int* flagI = flag;
  int* flagF = flag + 1;
  unsigned* gmax = poolz;
  float*    gsum = (float*)(poolz + 64);
  float*    gacc = (float*)(poolz + 128);

  // ---- dtype detection ----
  zero_u32<<<1, 256, 0, stream>>>((unsigned*)flag, 2);
  {
    int nprobe = in_sizes[0] < 32768 ? in_sizes[0] : 32768;
    detect_f32_k<<<(nprobe + 255)/256, 256, 0, stream>>>((const unsigned short*)d_in[0], nprobe, flagF);
    detect_i64<<<16, 256, 0, stream>>>(ei, flagI);
  }

  // ---- batched conversion: x, gate/fc params ----
  {
    static const int CIDX[5] = {0, 27, 28, 29, 30};
    bf16* CDST[5] = {cvx, cwg, cbg, cwfc, cbfc};
    CvPack p;
    int tot = 0;
    for (int t = 0; t < 5; ++t){
      p.src[t] = d_in[CIDX[t]];
      p.dst[t] = CDST[t];
      p.pre[t] = tot;
      tot += in_sizes[CIDX[t]];
    }
    p.pre[5] = tot;
    convert_all<<<(tot + 255)/256, 256, 0, stream>>>(p, flagF);
  }
  conv_idx<<<(N_EDGES + 255)/256, 256, 0, stream>>>(ei, braw, flagI, src, dst, bat);

  // ---- CSR ----
  zero_u32<<<(N_NODES + 255)/256, 256, 0, stream>>>((unsigned*)cnt, N_NODES);
  count_deg<<<(N_EDGES + 255)/256, 256, 0, stream>>>(dst, cnt);
  scan_deg<<<1, 1024, 0, stream>>>(cnt, row_ptr, fillp, N_NODES);
  fill_csr<<<(N_EDGES + 255)/256, 256, 0, stream>>>(dst, fillp, eids);

  // ---- grouped weight transposes + bias arrange ----
  transpose_grp<<<dim3(12800/32, 128/32), 256, 0, stream>>>(d_in[3],  d_in[5],  d_in[7],  d_in[9],  wcat1, 128, 512, GH, flagF);
  transpose_grp<<<dim3(6400/32,  512/32), 256, 0, stream>>>(d_in[11], d_in[13], d_in[15], d_in[17], wcat2, 512, 256, GH, flagF);
  transpose_grp<<<dim3(3200/32,  256/32), 256, 0, stream>>>(d_in[19], d_in[21], d_in[23], d_in[25], wcat3, 256, 128, GH, flagF);
  bias_arrange<<<(12800 + 255)/256, 256, 0, stream>>>(d_in[4],  d_in[6],  d_in[8],  d_in[10], bcat1, 512, GH, flagF);
  bias_arrange<<<(6400  + 255)/256, 256, 0, stream>>>(d_in[12], d_in[14], d_in[16], d_in[18], bcat2, 256, GH, flagF);
  bias_arrange<<<(3200  + 255)/256, 256, 0, stream>>>(d_in[20], d_in[22], d_in[24], d_in[26], bcat3, 128, GH, flagF);

  const int MT = (N_NODES + 127)/128;   // 79

  auto layer = [&](const bf16* hin, int Fin, int C,
                   const bf16* wcat, const bf16* bcat, bf16* hout){
    int total = N_NODES * C;
    int Wg = 3*GH*C;                 // group GEMM width (always multiple of 128)
    zero_u32<<<(total + 255)/256, 256, 0, stream>>>((unsigned*)accb, total);
    // skip projection (rows 24C..25C of wcat)
    gemm_bias<<<dim3(C/128, MT), 256, 0, stream>>>(hin, wcat + (size_t)24*C*Fin, bcat + 24*C, skipb, N_NODES, C, Fin);
    float scale = 1.0f/sqrtf((float)C);
    for (int g = 0; g < HG; ++g){
      gemm_bias<<<dim3(Wg/128, MT), 256, 0, stream>>>(hin, wcat + (size_t)g*Wg*Fin, bcat + g*Wg, QKVg, N_NODES, Wg, Fin);
      if (C == 512)      node_attn_g<8><<<N_NODES, 256, 0, stream>>>(QKVg, GH, row_ptr, eids, src, accb, scale);
      else if (C == 256) node_attn_g<4><<<N_NODES, 256, 0, stream>>>(QKVg, GH, row_ptr, eids, src, accb, scale);
      else               node_attn_g<2><<<N_NODES, 256, 0, stream>>>(QKVg, GH, row_ptr, eids, src, accb, scale);
    }
    finalize_layer<<<(total + 255)/256, 256, 0, stream>>>(accb, skipb, hout, total);
  };

  layer(cvx, 128, 512, wcat1, bcat1, h1);
  layer(h1,  512, 256, wcat2, bcat2, h2);
  layer(h2,  256, 128, wcat3, bcat3, h3);

  // ---- global attention pooling + fc ----
  zero_u32<<<(64 + 64 + 64*128 + 255)/256, 256, 0, stream>>>(poolz, 64 + 64 + 64*128);
  gate_compute<<<(N_NODES + 3)/4, 256, 0, stream>>>(h3, cwg, cbg, gate);
  gate_max<<<(N_NODES + 255)/256, 256, 0, stream>>>(gate, bat, gmax);
  gate_expsum<<<(N_NODES + 255)/256, 256, 0, stream>>>(gate, bat, gmax, gsum);
  pool_weighted<<<(N_NODES + 3)/4, 256, 0, stream>>>(gate, gsum, bat, h3, gacc);
  final_fc<<<N_GRAPHS, 64, 0, stream>>>(gacc, cwfc, cbfc, d_out, flagF);
}

// Round 7
// 945.875 us; speedup vs baseline: 2.4905x; 1.2310x over previous
//
#include <hip/hip_runtime.h>
#include <math.h>

typedef __bf16 bf16;
typedef __bf16 bf16x8 __attribute__((ext_vector_type(8)));
typedef float f32x4 __attribute__((ext_vector_type(4)));

#define N_NODES 10000
#define N_EDGES 80000
#define N_GRAPHS 64

template<int EPL> struct VecT;
template<> struct VecT<8>{ typedef bf16 type __attribute__((ext_vector_type(8))); };
template<> struct VecT<4>{ typedef bf16 type __attribute__((ext_vector_type(4))); };
template<> struct VecT<2>{ typedef bf16 type __attribute__((ext_vector_type(2))); };

__device__ inline unsigned f2ord(float f){
  unsigned u = __float_as_uint(f);
  return (u & 0x80000000u) ? ~u : (u | 0x80000000u);
}
__device__ inline float ord2f(unsigned u){
  return (u & 0x80000000u) ? __uint_as_float(u & 0x7fffffffu) : __uint_as_float(~u);
}

// async global->LDS, 16B per lane; LDS dest = base + lane*16 (wave-uniform base)
__device__ inline void gload_lds16(const bf16* g, bf16* l){
  __builtin_amdgcn_global_load_lds(
      (const __attribute__((address_space(1))) unsigned int*)g,
      (__attribute__((address_space(3))) unsigned int*)l, 16, 0, 0);
}

__global__ __launch_bounds__(256) void zero_u32(unsigned* __restrict__ p, int n){
  int i = blockIdx.x*256 + threadIdx.x;
  if (i < n) p[i] = 0u;
}

__global__ __launch_bounds__(256) void detect_f32_k(const unsigned short* __restrict__ raw, int n,
                                                    int* __restrict__ flagF){
  int i = blockIdx.x*256 + threadIdx.x;
  if (i < n){
    unsigned e = (raw[i] >> 7) & 0xFFu;
    if (e >= 0xC0u) atomicOr(flagF, 1);
  }
}

// ---- batched conversion of 5 small float tensors to bf16 ----
struct CvPack {
  const void* src[5];
  bf16* dst[5];
  int pre[6];
};
__global__ __launch_bounds__(256) void convert_all(CvPack p, const int* __restrict__ flagF){
  int gid = blockIdx.x*256 + threadIdx.x;
  if (gid >= p.pre[5]) return;
  int t = 0;
  while (gid >= p.pre[t+1]) ++t;
  int i = gid - p.pre[t];
  bool f = (*flagF != 0);
  p.dst[t][i] = f ? (bf16)((const float*)p.src[t])[i] : ((const bf16*)p.src[t])[i];
}

__global__ __launch_bounds__(256) void detect_i64(const int* __restrict__ raw, int* __restrict__ flag){
  int i = blockIdx.x*256 + threadIdx.x;
  if (i < 4000 && raw[2*i+1] != 0) atomicOr(flag, 1);   // flag!=0 => int32
}

__global__ __launch_bounds__(256) void conv_idx(const int* __restrict__ ei_raw,
                                                const int* __restrict__ b_raw,
                                                const int* __restrict__ flag,
                                                int* __restrict__ src, int* __restrict__ dst,
                                                int* __restrict__ bat){
  int i = blockIdx.x*256 + threadIdx.x;
  bool i32 = (*flag != 0);
  if (i < N_EDGES){
    int s = i32 ? ei_raw[i]   : ei_raw[2*i];
    int d = i32 ? ei_raw[N_EDGES + i] : ei_raw[2*(N_EDGES + i)];
    src[i] = min(max(s, 0), N_NODES-1);
    dst[i] = min(max(d, 0), N_NODES-1);
  }
  if (i < N_NODES){
    int b = i32 ? b_raw[i] : b_raw[2*i];
    bat[i] = min(max(b, 0), N_GRAPHS-1);
  }
}

// ---------------- CSR build ----------------
__global__ __launch_bounds__(256) void count_deg(const int* __restrict__ dst, int* __restrict__ cnt){
  int e = blockIdx.x*256 + threadIdx.x;
  if (e < N_EDGES) atomicAdd(&cnt[dst[e]], 1);
}

__global__ __launch_bounds__(1024) void scan_deg(const int* __restrict__ cnt,
                                                 int* __restrict__ row_ptr,
                                                 int* __restrict__ fill, int N){
  __shared__ int sdata[1024];
  __shared__ int soff;
  int tid = threadIdx.x;
  if (tid == 0){ soff = 0; row_ptr[0] = 0; }
  __syncthreads();
  for (int base = 0; base < N; base += 1024){
    int i = base + tid;
    int v = (i < N) ? cnt[i] : 0;
    sdata[tid] = v;
    __syncthreads();
    for (int d = 1; d < 1024; d <<= 1){
      int t = (tid >= d) ? sdata[tid - d] : 0;
      __syncthreads();
      sdata[tid] += t;
      __syncthreads();
    }
    int incl  = sdata[tid] + soff;
    int total = sdata[1023];
    if (i < N){ row_ptr[i+1] = incl; fill[i] = incl - v; }
    __syncthreads();
    if (tid == 0) soff += total;
    __syncthreads();
  }
}

__global__ __launch_bounds__(256) void fill_csr(const int* __restrict__ dst,
                                                int* __restrict__ fill, int* __restrict__ eids){
  int e = blockIdx.x*256 + threadIdx.x;
  if (e < N_EDGES){
    int p = atomicAdd(&fill[dst[e]], 1);
    eids[p] = e;
  }
}

// ---------------- grouped concat weight transpose ----------------
// out rows (25C total): [g*(3*GH*C) + {0:q,1:k,2:v}*GH*C + hh*C + cc] for head h=g*GH+hh,
// then [24C,25C) = skip. out[row][Fin] = w[Fin][col].
__global__ __launch_bounds__(256)
void transpose_grp(const void* __restrict__ wq, const void* __restrict__ wk,
                   const void* __restrict__ wv, const void* __restrict__ wsS,
                   bf16* __restrict__ out, int Fin, int C, int GH,
                   const int* __restrict__ flagF){
  __shared__ bf16 t[32][33];
  bool f = (*flagF != 0);
  int r0 = blockIdx.x * 32;
  const void* src; int colbase; int nstride;
  if (r0 < 24*C){
    int gw = 3*GH*C;
    int g = r0 / gw, rem = r0 - g*gw;
    int sec = rem / (GH*C);
    int hh  = (rem - sec*GH*C) / C;
    int cc  = rem % C;
    int h = g*GH + hh;
    src = (sec == 0) ? wq : (sec == 1) ? wk : wv;
    colbase = h*C + cc;
    nstride = 8*C;
  } else {
    src = wsS; colbase = r0 - 24*C; nstride = C;
  }
  int by = blockIdx.y;
  int x = threadIdx.x & 31, y = threadIdx.x >> 5;
  #pragma unroll
  for (int i = 0; i < 4; ++i){
    int r = by*32 + y + i*8;
    size_t idx = (size_t)r*nstride + colbase + x;
    t[y + i*8][x] = f ? (bf16)((const float*)src)[idx] : ((const bf16*)src)[idx];
  }
  __syncthreads();
  #pragma unroll
  for (int i = 0; i < 4; ++i){
    int orow = r0 + y + i*8;
    out[(size_t)orow*Fin + by*32 + x] = t[x][y + i*8];
  }
}

// grouped bias arrange: bcat[25C] in the same ordering
__global__ __launch_bounds__(256)
void bias_arrange(const void* __restrict__ bq, const void* __restrict__ bk,
                  const void* __restrict__ bv, const void* __restrict__ bs,
                  bf16* __restrict__ out, int C, int GH, const int* __restrict__ flagF){
  int j = blockIdx.x*256 + threadIdx.x;
  if (j >= 25*C) return;
  bool f = (*flagF != 0);
  const void* src; int idx;
  if (j < 24*C){
    int gw = 3*GH*C;
    int g = j / gw, rem = j - g*gw;
    int sec = rem / (GH*C);
    int hh  = (rem - sec*GH*C) / C;
    int cc  = rem % C;
    int h = g*GH + hh;
    src = (sec == 0) ? bq : (sec == 1) ? bk : bv;
    idx = h*C + cc;
  } else { src = bs; idx = j - 24*C; }
  out[j] = f ? (bf16)((const float*)src)[idx] : ((const bf16*)src)[idx];
}

// ---------------- GEMM: C[M][N] = A[M][K] @ Bt[N][K] + bias ----------------
__global__ __launch_bounds__(256)
void gemm_bias(const bf16* __restrict__ A, const bf16* __restrict__ Bt,
               const bf16* __restrict__ bias, bf16* __restrict__ Cout,
               int M, int N, int K)
{
  __shared__ bf16 As[128*64];
  __shared__ bf16 Bs[128*64];
  const int tid = threadIdx.x;
  const int lane = tid & 63;
  const int wave = tid >> 6;
  const int m0 = blockIdx.y * 128, n0 = blockIdx.x * 128;
  const int wm = (wave >> 1) * 64, wn = (wave & 1) * 64;
  const int l15 = lane & 15, l4 = lane >> 4;
  const int srow = lane >> 3;
  const int schunk = lane & 7;

  f32x4 acc[4][4] = {};

  for (int k0 = 0; k0 < K; k0 += 64){
    #pragma unroll
    for (int j = 0; j < 4; ++j){
      int r0 = (wave*4 + j)*8;
      int r  = r0 + srow;
      int gc = schunk ^ (r & 7);
      int ga = m0 + r; if (ga >= M) ga = M-1;
      gload_lds16(A  + (size_t)ga*K        + k0 + gc*8, As + r0*64);
      gload_lds16(Bt + (size_t)(n0 + r)*K  + k0 + gc*8, Bs + r0*64);
    }
    __syncthreads();
    #pragma unroll
    for (int kt = 0; kt < 2; ++kt){
      bf16x8 af[4], bfr[4];
      #pragma unroll
      for (int mt = 0; mt < 4; ++mt){
        int row = wm + mt*16 + l15;
        int p = (kt*4 + l4) ^ (l15 & 7);
        af[mt] = *(const bf16x8*)(As + row*64 + p*8);
      }
      #pragma unroll
      for (int nt = 0; nt < 4; ++nt){
        int row = wn + nt*16 + l15;
        int p = (kt*4 + l4) ^ (l15 & 7);
        bfr[nt] = *(const bf16x8*)(Bs + row*64 + p*8);
      }
      #pragma unroll
      for (int mt = 0; mt < 4; ++mt)
        #pragma unroll
        for (int nt = 0; nt < 4; ++nt)
          acc[mt][nt] = __builtin_amdgcn_mfma_f32_16x16x32_bf16(af[mt], bfr[nt], acc[mt][nt], 0, 0, 0);
    }
    __syncthreads();
  }

  #pragma unroll
  for (int nt = 0; nt < 4; ++nt){
    int col = n0 + wn + nt*16 + l15;
    float bv = (float)bias[col];
    #pragma unroll
    for (int mt = 0; mt < 4; ++mt){
      int rbase = m0 + wm + mt*16 + l4*4;
      #pragma unroll
      for (int r = 0; r < 4; ++r){
        int row = rbase + r;
        if (row < M) Cout[(size_t)row*N + col] = (bf16)(acc[mt][nt][r] + bv);
      }
    }
  }
}

// ---------------- two-pass per-node attention for one head group ----------------
// QKVg row layout: [q(GH*C) | k(GH*C) | v(GH*C)], stride S=3*GH*C.
// Block = 4 waves, wave w owns head w (requires GH<=4). Pass 1: 4 edges in
// flight per wave via 16-lane subgroups (coalesced 256B K chunks). Softmax to
// weights in LDS. Pass 2: shuffle-free weighted V accumulate.
// first: write accb (no read); last: read accb(if !first), apply mean+skip+ELU -> hout.
template<int C>
__global__ __launch_bounds__(256)
void node_attn_2p(const bf16* __restrict__ QKVg, int GH,
                  const int* __restrict__ row_ptr, const int* __restrict__ eids,
                  const int* __restrict__ srcv, float* __restrict__ accb,
                  const bf16* __restrict__ skipb, bf16* __restrict__ hout,
                  float scale, int first, int last)
{
  constexpr int EPL = C/64;     // pass-2 channels per lane
  constexpr int NQ  = C/128;    // 128-channel chunks (8 ch/lane per 16-lane subgroup)
  typedef typename VecT<EPL>::type vecb;
  __shared__ int   sSrc[256];
  __shared__ float sw[4][256];
  __shared__ float red[4][C];

  int n = blockIdx.x;
  int beg = row_ptr[n], deg = row_ptr[n+1] - beg;
  if (deg > 256) deg = 256;     // deg ~ Poisson(8); P(deg>256) ~ 0
  int wave = threadIdx.x >> 6, lane = threadIdx.x & 63;
  int sub = lane >> 4, sl = lane & 15;
  const int S = 3*GH*C;
  const int h = wave;
  const bool act = (wave < GH) && (deg > 0);

  for (int i = threadIdx.x; i < deg; i += 256) sSrc[i] = srcv[eids[beg + i]];
  __syncthreads();

  float acc[EPL];
  #pragma unroll
  for (int k = 0; k < EPL; ++k) acc[k] = 0.f;

  if (act){
    // ---- pass 1: scores (4 edges in flight; subgroup = 16 lanes) ----
    float q[NQ*8];
    const bf16* qp = QKVg + (size_t)n*S + h*C;
    #pragma unroll
    for (int c = 0; c < NQ; ++c){
      bf16x8 qv = *(const bf16x8*)(qp + c*128 + sl*8);
      #pragma unroll
      for (int j = 0; j < 8; ++j) q[c*8+j] = (float)qv[j];
    }
    for (int i0 = 0; i0 < deg; i0 += 4){
      int e = i0 + sub;
      float s = 0.f;
      if (e < deg){
        const bf16* kp = QKVg + (size_t)sSrc[e]*S + GH*C + h*C;
        #pragma unroll
        for (int c = 0; c < NQ; ++c){
          bf16x8 kv = *(const bf16x8*)(kp + c*128 + sl*8);
          #pragma unroll
          for (int j = 0; j < 8; ++j) s += q[c*8+j]*(float)kv[j];
        }
      }
      #pragma unroll
      for (int o = 1; o < 16; o <<= 1) s += __shfl_xor(s, o, 64);
      if (sl == 0 && e < deg) sw[wave][e] = s * scale;
    }
    // ---- softmax -> weights in LDS (same wave only; in-order LDS) ----
    float m = -3.4e38f;
    for (int i = lane; i < deg; i += 64) m = fmaxf(m, sw[wave][i]);
    #pragma unroll
    for (int o = 32; o; o >>= 1) m = fmaxf(m, __shfl_xor(m, o, 64));
    float ss = 0.f;
    for (int i = lane; i < deg; i += 64) ss += __expf(sw[wave][i] - m);
    #pragma unroll
    for (int o = 32; o; o >>= 1) ss += __shfl_xor(ss, o, 64);
    float inv = 1.f/(ss + 1e-16f);
    for (int i = lane; i < deg; i += 64) sw[wave][i] = __expf(sw[wave][i] - m)*inv;
    // ---- pass 2: shuffle-free weighted V accumulate ----
    for (int i = 0; i < deg; ++i){
      float w = sw[wave][i];
      vecb vv = *(const vecb*)(QKVg + (size_t)sSrc[i]*S + 2*GH*C + h*C + lane*EPL);
      #pragma unroll
      for (int k = 0; k < EPL; ++k) acc[k] += w*(float)vv[k];
    }
  }

  #pragma unroll
  for (int k = 0; k < EPL; ++k) red[wave][lane*EPL + k] = acc[k];
  __syncthreads();
  for (int idx = threadIdx.x; idx < C; idx += 256){
    float sm = red[0][idx] + red[1][idx] + red[2][idx] + red[3][idx];
    size_t o = (size_t)n*C + idx;
    if (last){
      float base = first ? 0.f : accb[o];
      float v = (base + sm)*0.125f + (float)skipb[o];
      v = (v > 0.f) ? v : (__expf(v) - 1.f);
      hout[o] = (bf16)v;
    } else if (first){
      accb[o] = sm;
    } else {
      accb[o] += sm;
    }
  }
}

// ---------------- pooling ----------------
__global__ __launch_bounds__(256) void gate_compute(const bf16* __restrict__ h, const bf16* __restrict__ wg,
                                                    const bf16* __restrict__ bg, float* __restrict__ gate){
  int n = blockIdx.x*4 + (threadIdx.x >> 6);
  if (n >= N_NODES) return;
  int lane = threadIdx.x & 63;
  const bf16* hr = h + (size_t)n*128;
  float s = (float)hr[lane]*(float)wg[lane] + (float)hr[64+lane]*(float)wg[64+lane];
  #pragma unroll
  for (int o = 32; o; o >>= 1) s += __shfl_xor(s, o, 64);
  if (lane == 0) gate[n] = s + (float)bg[0];
}

__global__ __launch_bounds__(256) void gate_max(const float* __restrict__ gate, const int* __restrict__ bat,
                                                unsigned* __restrict__ gmax){
  int n = blockIdx.x*256 + threadIdx.x;
  if (n < N_NODES) atomicMax(&gmax[bat[n]], f2ord(gate[n]));
}

__global__ __launch_bounds__(256) void gate_expsum(float* __restrict__ gate, const int* __restrict__ bat,
                                                   const unsigned* __restrict__ gmax, float* __restrict__ gsum){
  int n = blockIdx.x*256 + threadIdx.x;
  if (n < N_NODES){
    float e = __expf(gate[n] - ord2f(gmax[bat[n]]));
    gate[n] = e;
    atomicAdd(&gsum[bat[n]], e);
  }
}

__global__ __launch_bounds__(256) void pool_weighted(const float* __restrict__ gate, const float* __restrict__ gsum,
                                                     const int* __restrict__ bat, const bf16* __restrict__ h,
                                                     float* __restrict__ gacc){
  int n = blockIdx.x*4 + (threadIdx.x >> 6);
  if (n >= N_NODES) return;
  int lane = threadIdx.x & 63;
  int b = bat[n];
  float w = gate[n]/(gsum[b] + 1e-16f);
  atomicAdd(&gacc[b*128 + lane],      w*(float)h[(size_t)n*128 + lane]);
  atomicAdd(&gacc[b*128 + 64 + lane], w*(float)h[(size_t)n*128 + 64 + lane]);
}

__global__ __launch_bounds__(64) void final_fc(const float* __restrict__ gacc, const bf16* __restrict__ wfc,
                                               const bf16* __restrict__ bfc, void* __restrict__ out,
                                               const int* __restrict__ flagF){
  int g = blockIdx.x;
  int o = threadIdx.x;
  if (o < 10){
    float s = (float)bfc[o];
    for (int c = 0; c < 128; ++c) s += gacc[g*128 + c]*(float)wfc[c*10 + o];
    if (*flagF) ((float*)out)[(size_t)g*10 + o] = s;
    else        ((bf16*)out)[(size_t)g*10 + o]  = (bf16)s;
  }
}

extern "C" void kernel_launch(void* const* d_in, const int* in_sizes, int n_in,
                              void* d_out, int out_size, void* d_ws, size_t ws_size,
                              hipStream_t stream)
{
  const int* ei   = (const int*)d_in[1];
  const int* braw = (const int*)d_in[2];

  bf16 *QKVg=0, *skipb=0, *h1=0, *h2=0, *h3=0, *cvx=0;
  bf16 *wcat1=0,*wcat2=0,*wcat3=0,*bcat1=0,*bcat2=0,*bcat3=0;
  bf16 *cwg=0,*cbg=0,*cwfc=0,*cbfc=0;
  float *accb=0,*gate=0;
  int *src=0,*dst=0,*bat=0,*cnt=0,*row_ptr=0,*fillp=0,*eids=0,*flag=0;
  unsigned* poolz=0;

  auto plan = [&](int GH)->size_t{
    size_t off = 0;
    auto A = [&](size_t bytes)->char*{
      char* p = (char*)d_ws + off;
      off += (bytes + 255) & ~(size_t)255;
      return p;
    };
    QKVg = (bf16*)A((size_t)N_NODES*3*GH*512*2);
    accb = (float*)A((size_t)N_NODES*512*4);
    skipb= (bf16*) A((size_t)N_NODES*512*2);
    h1   = (bf16*) A((size_t)N_NODES*512*2);
    h2   = (bf16*) A((size_t)N_NODES*256*2);
    h3   = (bf16*) A((size_t)N_NODES*128*2);
    cvx  = (bf16*) A((size_t)N_NODES*128*2);
    wcat1= (bf16*) A((size_t)12800*128*2);
    wcat2= (bf16*) A((size_t)6400*512*2);
    wcat3= (bf16*) A((size_t)3200*256*2);
    bcat1= (bf16*) A(12800*2);
    bcat2= (bf16*) A(6400*2);
    bcat3= (bf16*) A(3200*2);
    cwg  = (bf16*) A(128*2);
    cbg  = (bf16*) A(2*2);
    cwfc = (bf16*) A(1280*2);
    cbfc = (bf16*) A(10*2);
    src  = (int*)  A((size_t)N_EDGES*4);
    dst  = (int*)  A((size_t)N_EDGES*4);
    bat  = (int*)  A((size_t)N_NODES*4);
    cnt  = (int*)  A((size_t)N_NODES*4);
    row_ptr=(int*) A((size_t)(N_NODES+1)*4);
    fillp= (int*)  A((size_t)N_NODES*4);
    eids = (int*)  A((size_t)N_EDGES*4);
    flag = (int*)  A(256);
    gate = (float*)A((size_t)N_NODES*4);
    poolz= (unsigned*)A((size_t)(64 + 64 + 64*128)*4);
    return off;
  };

  int GH = 4;                       // node_attn_2p requires GH<=4 (wave==head)
  while (GH > 1 && plan(GH) > ws_size) GH >>= 1;
  if (plan(GH) > ws_size) return;   // floor plan doesn't fit; visible failure
  const int HG = 8 / GH;

  int* flagI = flag;
  int* flagF = flag + 1;
  unsigned* gmax = poolz;
  float*    gsum = (float*)(poolz + 64);
  float*    gacc = (float*)(poolz + 128);

  // ---- dtype detection ----
  zero_u32<<<1, 256, 0, stream>>>((unsigned*)flag, 2);
  {
    int nprobe = in_sizes[0] < 32768 ? in_sizes[0] : 32768;
    detect_f32_k<<<(nprobe + 255)/256, 256, 0, stream>>>((const unsigned short*)d_in[0], nprobe, flagF);
    detect_i64<<<16, 256, 0, stream>>>(ei, flagI);
  }

  // ---- batched conversion: x, gate/fc params ----
  {
    static const int CIDX[5] = {0, 27, 28, 29, 30};
    bf16* CDST[5] = {cvx, cwg, cbg, cwfc, cbfc};
    CvPack p;
    int tot = 0;
    for (int t = 0; t < 5; ++t){
      p.src[t] = d_in[CIDX[t]];
      p.dst[t] = CDST[t];
      p.pre[t] = tot;
      tot += in_sizes[CIDX[t]];
    }
    p.pre[5] = tot;
    convert_all<<<(tot + 255)/256, 256, 0, stream>>>(p, flagF);
  }
  conv_idx<<<(N_EDGES + 255)/256, 256, 0, stream>>>(ei, braw, flagI, src, dst, bat);

  // ---- CSR ----
  zero_u32<<<(N_NODES + 255)/256, 256, 0, stream>>>((unsigned*)cnt, N_NODES);
  count_deg<<<(N_EDGES + 255)/256, 256, 0, stream>>>(dst, cnt);
  scan_deg<<<1, 1024, 0, stream>>>(cnt, row_ptr, fillp, N_NODES);
  fill_csr<<<(N_EDGES + 255)/256, 256, 0, stream>>>(dst, fillp, eids);

  // ---- grouped weight transposes + bias arrange ----
  transpose_grp<<<dim3(12800/32, 128/32), 256, 0, stream>>>(d_in[3],  d_in[5],  d_in[7],  d_in[9],  wcat1, 128, 512, GH, flagF);
  transpose_grp<<<dim3(6400/32,  512/32), 256, 0, stream>>>(d_in[11], d_in[13], d_in[15], d_in[17], wcat2, 512, 256, GH, flagF);
  transpose_grp<<<dim3(3200/32,  256/32), 256, 0, stream>>>(d_in[19], d_in[21], d_in[23], d_in[25], wcat3, 256, 128, GH, flagF);
  bias_arrange<<<(12800 + 255)/256, 256, 0, stream>>>(d_in[4],  d_in[6],  d_in[8],  d_in[10], bcat1, 512, GH, flagF);
  bias_arrange<<<(6400  + 255)/256, 256, 0, stream>>>(d_in[12], d_in[14], d_in[16], d_in[18], bcat2, 256, GH, flagF);
  bias_arrange<<<(3200  + 255)/256, 256, 0, stream>>>(d_in[20], d_in[22], d_in[24], d_in[26], bcat3, 128, GH, flagF);

  const int MT = (N_NODES + 127)/128;   // 79

  auto layer = [&](const bf16* hin, int Fin, int C,
                   const bf16* wcat, const bf16* bcat, bf16* hout){
    int Wg = 3*GH*C;
    // skip projection (rows 24C..25C of wcat)
    gemm_bias<<<dim3(C/128, MT), 256, 0, stream>>>(hin, wcat + (size_t)24*C*Fin, bcat + 24*C, skipb, N_NODES, C, Fin);
    float scale = 1.0f/sqrtf((float)C);
    for (int g = 0; g < HG; ++g){
      gemm_bias<<<dim3(Wg/128, MT), 256, 0, stream>>>(hin, wcat + (size_t)g*Wg*Fin, bcat + g*Wg, QKVg, N_NODES, Wg, Fin);
      int first = (g == 0), last = (g == HG-1);
      if (C == 512)      node_attn_2p<512><<<N_NODES, 256, 0, stream>>>(QKVg, GH, row_ptr, eids, src, accb, skipb, hout, scale, first, last);
      else if (C == 256) node_attn_2p<256><<<N_NODES, 256, 0, stream>>>(QKVg, GH, row_ptr, eids, src, accb, skipb, hout, scale, first, last);
      else               node_attn_2p<128><<<N_NODES, 256, 0, stream>>>(QKVg, GH, row_ptr, eids, src, accb, skipb, hout, scale, first, last);
    }
  };

  layer(cvx, 128, 512, wcat1, bcat1, h1);
  layer(h1,  512, 256, wcat2, bcat2, h2);
  layer(h2,  256, 128, wcat3, bcat3, h3);

  // ---- global attention pooling + fc ----
  zero_u32<<<(64 + 64 + 64*128 + 255)/256, 256, 0, stream>>>(poolz, 64 + 64 + 64*128);
  gate_compute<<<(N_NODES + 3)/4, 256, 0, stream>>>(h3, cwg, cbg, gate);
  gate_max<<<(N_NODES + 255)/256, 256, 0, stream>>>(gate, bat, gmax);
  gate_expsum<<<(N_NODES + 255)/256, 256, 0, stream>>>(gate, bat, gmax, gsum);
  pool_weighted<<<(N_NODES + 3)/4, 256, 0, stream>>>(gate, gsum, bat, h3, gacc);
  final_fc<<<N_GRAPHS, 64, 0, stream>>>(gacc, cwfc, cbfc, d_out, flagF);
}